// Round 10
// baseline (159.550 us; speedup 1.0000x reference)
//
#include <hip/hip_runtime.h>
#include <hip/hip_bf16.h>

// Problem constants: B=4, C=64, H=W=64, HW=4096, P=64, Q=3 (CQ=192)
namespace {
constexpr int IMG    = 262144;   // 64*4096 elems per batch image
constexpr int PADIMG = 4356;     // 66*66 padded pixels
constexpr float LOG2E = 1.44269504088896340736f;
// workspace float offsets
constexpr int WBFO  = 0;         // fp16 weights: wbot[9][6][64][32], wout[9][6][64][32], wtop[6][64][32], wcen[6][64][32]
constexpr int XPADO = 122880;    // fp16 xp/up padded [b][ck 6][px 4356][32] (aliased: xp then up)
constexpr int TOPO  = 1795584;   // fp16 topT [b][m][p]
constexpr int CENO  = 2319872;   // fp16 cenT [b][n][p]
constexpr int BOTO  = 2844160;   // fp16 bot  [b][c][m]
constexpr int PVO   = 3368448;   // bf16 PV [ms][b][n][c]
// M/Z scratch [s][b 4][group 128]: placement depends on m-split count (PV size)
constexpr int MSO4  = 5465600;   // ms=4 legacy layout (PV = 8MB)
constexpr int MSO8  = 7562752;   // ms=8 layout (PV = 16MB)
constexpr size_t NEED8 = (size_t)(MSO8 + 8192) * 4;   // ~30.3 MB workspace for ms=8
}

using half8v  = __attribute__((ext_vector_type(8))) _Float16;
using half4v  = __attribute__((ext_vector_type(4))) _Float16;
using short8v = __attribute__((ext_vector_type(8))) short;
using short4v = __attribute__((ext_vector_type(4))) short;
using uint4v  = __attribute__((ext_vector_type(4))) unsigned;
typedef __attribute__((ext_vector_type(4))) float f32x4;

__device__ __forceinline__ short f2bf(float f) {
    __hip_bfloat16 h = __float2bfloat16(f);
    return *reinterpret_cast<short*>(&h);
}
__device__ __forceinline__ float bf2f(short s) {
    unsigned u = ((unsigned)(unsigned short)s) << 16;
    return __uint_as_float(u);
}
__device__ __forceinline__ unsigned pkrtz(float a, float b) {
    return __builtin_bit_cast(unsigned, __builtin_amdgcn_cvt_pkrtz(a, b));
}
// async global->LDS, 16B/lane. LDS dest is wave-uniform base + lane*16 (m104);
// pass the uniform base, per-lane global src.
__device__ __forceinline__ void gload16(const void* g, void* l) {
    __builtin_amdgcn_global_load_lds(
        (const __attribute__((address_space(1))) unsigned*)g,
        (__attribute__((address_space(3))) unsigned*)l, 16, 0, 0);
}

// ---- Dispatch 1: weights->fp16 reorder into k-chunked layouts (blocks 0..959)
// + x-powers into chunked padded xpad incl. border zeroing (blocks 960..1215).
__global__ __launch_bounds__(256) void k_prep(const float* __restrict__ bw, const float* __restrict__ ow,
                                              const float* __restrict__ tw, const float* __restrict__ cw,
                                              _Float16* __restrict__ wbf,
                                              const float* __restrict__ x, _Float16* __restrict__ xpad) {
    __shared__ float xs[64 * 65];
    int bx = blockIdx.x, t = threadIdx.x;
    if (bx < 960) {
        int idx = bx * 256 + t;   // < 245760
        if (idx < 221184) {
            // 3x3: w[o][(p*64+ci)*9+tap] -> wT[tap][ck][o][ki]  (k = ck*32+ki = p*64+ci)
            int tsel = idx / 110592;
            int r    = idx - tsel * 110592;
            int tap  = r / 12288;
            int rr   = r - tap * 12288;
            int ck   = rr / 2048;
            int r2   = rr - ck * 2048;
            int o    = r2 >> 5;
            int ki   = r2 & 31;
            int k    = ck * 32 + ki;
            int p    = k >> 6, ci = k & 63;
            const float* src = tsel ? ow : bw;
            wbf[idx] = (_Float16)src[o * 1728 + (p * 64 + ci) * 9 + tap];
        } else {
            // 1x1: w[o][192] -> wT[ck][o][ki]; center pre-scaled by log2(e)
            int j = idx - 221184;
            int tsel = j / 12288;
            int rr   = j - tsel * 12288;
            int ck   = rr / 2048;
            int r2   = rr - ck * 2048;
            int o    = r2 >> 5;
            int ki   = r2 & 31;
            int k    = ck * 32 + ki;
            wbf[idx] = (_Float16)(tsel ? cw[o * 192 + k] * LOG2E : tw[o * 192 + k]);
        }
        return;
    }
    int bx2 = bx - 960;
    int b = bx2 >> 6, h = bx2 & 63;
    // zero this block's share of the pad border across all 6 chunk planes
    {
        _Float16* base = xpad + (size_t)b * 6 * PADIMG * 32;
        int px[6];
        px[0] = (h + 1) * 66;
        px[1] = (h + 1) * 66 + 65;
        px[2] = h;
        px[3] = 65 * 66 + h;
        int npx = 4;
        if (h < 2) { px[4] = 64 + h; px[5] = 65 * 66 + 64 + h; npx = 6; }
        int pi = t / 24, ck = t % 24;
        if (pi < npx) {
            int cp = ck >> 2, q = ck & 3;
            half8v z = {0, 0, 0, 0, 0, 0, 0, 0};
            *(half8v*)&base[((size_t)cp * PADIMG + px[pi]) * 32 + q * 8] = z;
        }
    }
    #pragma unroll
    for (int it = 0; it < 16; ++it) {
        int idx = it * 256 + t;
        int ci = idx >> 6, wc = idx & 63;
        xs[ci * 65 + wc] = x[b * IMG + ci * 4096 + h * 64 + wc];
    }
    __syncthreads();
    _Float16* dst = xpad + ((size_t)b * 6 * PADIMG + (h + 1) * 66 + 1) * 32;
    #pragma unroll
    for (int it = 0; it < 6; ++it) {
        int u = it * 256 + t;
        int ck = u >> 8, within = u & 255;
        int px = within >> 2, q = within & 3;
        int k0 = ck * 32 + q * 8;
        int p = k0 >> 6, c0 = k0 & 63;
        half8v o;
        #pragma unroll
        for (int j = 0; j < 8; ++j) {
            float v = xs[(c0 + j) * 65 + px];
            float pw = (p == 0) ? v : ((p == 1) ? v * v : v * v * v);
            o[j] = (_Float16)pw;
        }
        *(half8v*)&dst[((size_t)ck * PADIMG + px) * 32 + q * 8] = o;
    }
}

// 3x3 SelfONN conv, full-K MFMA implicit GEMM, 32 oc/block, direct output+bias.
// R10: tap loop fully unrolled (kills per-tap div/mod, lets the compiler batch
// the 18 loads per tap with static offsets).
__device__ __forceinline__ void conv3d32(int bx, int t,
                                         const _Float16* __restrict__ src,
                                         const _Float16* __restrict__ wt,
                                         const float* __restrict__ bias,
                                         _Float16* __restrict__ dh_, float* __restrict__ df) {
    int lane = t & 63, w = t >> 6;
    int l16 = lane & 15, quad = lane >> 4;
    int oh = bx >> 8, mt = bx & 255;
    int b = mt >> 6, h = mt & 63;
    const _Float16* abase = src + ((size_t)b * 6 * PADIMG + (h + 1) * 66 + 1 + w * 16 + l16) * 32 + quad * 8;
    const _Float16* bbase = wt + (size_t)(oh * 32 + l16) * 32 + quad * 8;
    f32x4 acc[2];
    acc[0] = (f32x4){0.f, 0.f, 0.f, 0.f};
    acc[1] = (f32x4){0.f, 0.f, 0.f, 0.f};
    #pragma unroll
    for (int tap = 0; tap < 9; ++tap) {
        int dh = tap / 3 - 1, dw = tap % 3 - 1;
        const _Float16* arow = abase + (dh * 66 + dw) * 32;
        const _Float16* brow = bbase + (size_t)tap * 6 * 2048;
        #pragma unroll
        for (int c6 = 0; c6 < 6; ++c6) {
            half8v afr  = *(const half8v*)&arow[(size_t)c6 * PADIMG * 32];
            half8v bfr0 = *(const half8v*)&brow[(size_t)c6 * 2048];
            half8v bfr1 = *(const half8v*)&brow[(size_t)c6 * 2048 + 512];
            acc[0] = __builtin_amdgcn_mfma_f32_16x16x32_f16(afr, bfr0, acc[0], 0, 0, 0);
            acc[1] = __builtin_amdgcn_mfma_f32_16x16x32_f16(afr, bfr1, acc[1], 0, 0, 0);
        }
    }
    #pragma unroll
    for (int nf = 0; nf < 2; ++nf) {
        int c = oh * 32 + nf * 16 + l16;
        float bv = bias[c];
        size_t oi = (size_t)b * 262144 + (size_t)c * 4096 + h * 64 + w * 16 + quad * 4;
        if (dh_) {
            half4v o;
            #pragma unroll
            for (int r = 0; r < 4; ++r) o[r] = (_Float16)(acc[nf][r] + bv);
            *(half4v*)&dh_[oi] = o;
        } else {
            float4 o = make_float4(acc[nf][0] + bv, acc[nf][1] + bv, acc[nf][2] + bv, acc[nf][3] + bv);
            *(float4*)&df[oi] = o;
        }
    }
}

// ---- Dispatch 2: conv3-bottom (blocks 0..511, direct fp16 out, oc-32) + fused
// top/center 1x1 convs (blocks 512..1023).
__global__ __launch_bounds__(256) void k_convs(const _Float16* __restrict__ xpad,
                                               const _Float16* __restrict__ wbf,
                                               const float* __restrict__ tb, const float* __restrict__ cb,
                                               const float* __restrict__ bbias,
                                               _Float16* __restrict__ topd, _Float16* __restrict__ cend,
                                               _Float16* __restrict__ botb) {
    int bx = blockIdx.x, t = threadIdx.x;
    if (bx < 512) {
        conv3d32(bx, t, xpad, wbf /* wbot at offset 0 */, bbias, botb, nullptr);
        return;
    }
    int bx2 = bx - 512;
    int lane = t & 63, w = t >> 6;
    int l16 = lane & 15, quad = lane >> 4;
    int ot = bx2 >> 8, mt = bx2 & 255;
    int b = mt >> 6, h = mt & 63;
    const _Float16* wt   = wbf + (ot ? 233472 : 221184);   // wcen : wtop
    const float*    bias = ot ? cb : tb;
    _Float16*       dst  = (ot ? cend : topd) + (size_t)b * IMG;
    const _Float16* abase = xpad + ((size_t)b * 6 * PADIMG + (h + 1) * 66 + 1 + w * 16 + l16) * 32 + quad * 8;
    const _Float16* bbase = wt + (size_t)l16 * 32 + quad * 8;
    f32x4 acc[4];
    #pragma unroll
    for (int nf = 0; nf < 4; ++nf) acc[nf] = (f32x4){0.f, 0.f, 0.f, 0.f};
    #pragma unroll
    for (int kc = 0; kc < 6; ++kc) {
        half8v afr = *(const half8v*)&abase[(size_t)kc * PADIMG * 32];
        #pragma unroll
        for (int nf = 0; nf < 4; ++nf) {
            half8v bfr = *(const half8v*)&bbase[(size_t)kc * 2048 + nf * 16 * 32];
            acc[nf] = __builtin_amdgcn_mfma_f32_16x16x32_f16(afr, bfr, acc[nf], 0, 0, 0);
        }
    }
    _Float16* dp = dst + (size_t)(h * 64 + w * 16) * 64;
    #pragma unroll
    for (int nf = 0; nf < 4; ++nf) {
        float bv = bias[nf * 16 + l16];
        if (ot) bv *= LOG2E;   // center output lives in log2e-scaled domain
        #pragma unroll
        for (int r = 0; r < 4; ++r)
            dp[(quad * 4 + r) * 64 + nf * 16 + l16] = (_Float16)(acc[nf][r] + bv);
    }
}

// ---- Dispatch 3: fp16 MFMA flash attention, global softmax (R10).
// At 4 waves/SIMD (R9's occupancy win), the DS pipe is the heaviest consumer
// (~13us base + 3.4us measured conflicts). Changes:
//  (1) UNPADDED [64][64] LDS with XOR swizzle: read addr = row*64 +
//      (col ^ ((l16&7)*8)). Bank-optimal: each ds_read_b128 hits exactly
//      8 lanes per 4-bank slot (the b128 minimum) -> conflicts ~0.
//      LDS 36.9KB -> 32KB.
//  (2) global_load_lds (16B) staging with PRE-SWIZZLED global source
//      (rule21/m173: linear LDS dest = wave-uniform base + lane*16, which the
//      staging layout already is; swizzle moves to the per-lane global offset
//      ((t&7)^(r&7))*8 — same involution as the read XOR). Frees the rt/rb
//      prefetch registers (-16 regs, relieves 128-bound spills) and deletes
//      4 VMEM + 4 ds_write per wave-tile.
// Loop: barrier; issue gloads(next buf); compute(cur buf) — 1 barrier/tile;
// the pre-barrier vmcnt(0) drains loads issued a full compute-phase earlier.
// Rest = R9: launch_bounds(256,4), in-reg P via permlane32+16, defer-max.
template<int MT>
__global__ __launch_bounds__(256, 4) void k_attn(float* __restrict__ ws, int msoOff, int zsoOff) {
    __shared__ _Float16 ltop[2][64 * 64];    // [buf][m][p swizzled]
    __shared__ _Float16 lbot[2][64 * 64];    // [buf][c][m swizzled]
    int t    = threadIdx.x;
    int lane = t & 63, w = t >> 6;
    int l16  = lane & 15, quad = lane >> 4;
    int bxr = blockIdx.x;
    int bx  = (bxr & 7) * ((int)gridDim.x >> 3) + (bxr >> 3);
    int st = bx & 31, b = (bx >> 5) & 3, s = bx >> 7;
    int n0 = st * 128;
    int mbase = s * MT * 64;
    const _Float16* topg = (const _Float16*)(ws + TOPO) + (size_t)b * IMG;
    const _Float16* ceng = (const _Float16*)(ws + CENO) + (size_t)b * IMG;
    const _Float16* botg = (const _Float16*)(ws + BOTO) + (size_t)b * IMG;

    // staging geometry: lane t covers LDS linear slot t*16B = row (t>>3),
    // col (t&7)*16B; source col pre-swizzled so reads can XOR-deswizzle.
    int r0   = t >> 3;                       // 0..31 (and +32 for 2nd half)
    int swz0 = ((t & 7) ^ (r0 & 7)) * 8;     // halves
    int rsw  = (l16 & 7) * 8;                // read-side XOR (halves)

    auto stage = [&](int buf, int mt) {
        gload16(topg + (size_t)(mt + r0) * 64 + swz0,      &ltop[buf][w * 512]);
        gload16(topg + (size_t)(mt + r0 + 32) * 64 + swz0, &ltop[buf][2048 + w * 512]);
        gload16(botg + (size_t)r0 * 4096 + mt + swz0,      &lbot[buf][w * 512]);
        gload16(botg + (size_t)(r0 + 32) * 4096 + mt + swz0, &lbot[buf][2048 + w * 512]);
    };

    // B-frag of QK^T: cen, register-resident. lane l16 = n-col, quad*8 = k(p)
    half8v bcen[2][2];   // [nj][kk]
    #pragma unroll
    for (int nj = 0; nj < 2; ++nj)
        #pragma unroll
        for (int kk = 0; kk < 2; ++kk)
            bcen[nj][kk] = *(const half8v*)&ceng[(size_t)(n0 + w * 32 + nj * 16 + l16) * 64 + kk * 32 + quad * 8];

    f32x4 pv[4][2];   // O^T frags: [cj][nj], row c = cj*16+quad*4+r, col n = nj*16+l16
    #pragma unroll
    for (int cj = 0; cj < 4; ++cj)
        #pragma unroll
        for (int nj = 0; nj < 2; ++nj) pv[cj][nj] = (f32x4){0.f, 0.f, 0.f, 0.f};
    float runm = -3.0e38f, zacc = 0.f;

    stage(0, mbase);

    #pragma unroll
    for (int tt = 0; tt < MT; ++tt) {
        const _Float16* lt = ltop[tt & 1];
        const _Float16* lb = lbot[tt & 1];
        __syncthreads();   // drains this wave's gloads; prev compute done block-wide
        if (tt + 1 < MT) stage((tt + 1) & 1, mbase + (tt + 1) * 64);
        // S^T = top * cen^T: sa[mi][nj], row m = mi*16+quad*4+r, col n = nj*16+l16
        f32x4 sa[4][2];
        #pragma unroll
        for (int mi = 0; mi < 4; ++mi)
            #pragma unroll
            for (int nj = 0; nj < 2; ++nj) sa[mi][nj] = (f32x4){0.f, 0.f, 0.f, 0.f};
        __builtin_amdgcn_s_setprio(1);
        #pragma unroll
        for (int kk = 0; kk < 2; ++kk)
            #pragma unroll
            for (int mi = 0; mi < 4; ++mi) {
                half8v at = *(half8v*)&lt[(mi * 16 + l16) * 64 + ((kk * 32 + quad * 8) ^ rsw)];
                sa[mi][0] = __builtin_amdgcn_mfma_f32_16x16x32_f16(at, bcen[0][kk], sa[mi][0], 0, 0, 0);
                sa[mi][1] = __builtin_amdgcn_mfma_f32_16x16x32_f16(at, bcen[1][kk], sa[mi][1], 0, 0, 0);
            }
        __builtin_amdgcn_s_setprio(0);
        // lane-local tile max
        float lm = -3.0e38f;
        #pragma unroll
        for (int mi = 0; mi < 4; ++mi)
            #pragma unroll
            for (int nj = 0; nj < 2; ++nj) {
                float a  = fmaxf(sa[mi][nj][0], sa[mi][nj][1]);
                float c2 = fmaxf(sa[mi][nj][2], sa[mi][nj][3]);
                lm = fmaxf(lm, fmaxf(a, c2));
            }
        // T13 defer-max: only reduce+rescale when some lane exceeds runm+8
        if (!__all(lm - runm <= 8.0f)) {
            float tm = lm;
            for (int o2 = 32; o2; o2 >>= 1) tm = fmaxf(tm, __shfl_xor(tm, o2, 64));
            if (tm > runm) {
                float sc = __builtin_amdgcn_exp2f(runm - tm);
                zacc *= sc;
                #pragma unroll
                for (int cj = 0; cj < 4; ++cj)
                    #pragma unroll
                    for (int nj = 0; nj < 2; ++nj) pv[cj][nj] *= sc;
                runm = tm;
            }
        }
        // Per kb (32-m half): exp2 -> fp16 pack -> pure-VALU quad exchange -> PV
        #pragma unroll
        for (int kb = 0; kb < 2; ++kb) {
            unsigned pk[2][2][2];   // [f = mi&1][nj][d]
            #pragma unroll
            for (int f = 0; f < 2; ++f) {
                int mi = 2 * kb + f;
                #pragma unroll
                for (int nj = 0; nj < 2; ++nj) {
                    float e0 = __builtin_amdgcn_exp2f(sa[mi][nj][0] - runm);
                    float e1 = __builtin_amdgcn_exp2f(sa[mi][nj][1] - runm);
                    float e2 = __builtin_amdgcn_exp2f(sa[mi][nj][2] - runm);
                    float e3 = __builtin_amdgcn_exp2f(sa[mi][nj][3] - runm);
                    zacc += (e0 + e1) + (e2 + e3);
                    pk[f][nj][0] = pkrtz(e0, e1);
                    pk[f][nj][1] = pkrtz(e2, e3);
                }
            }
            // Exchange: dst lane(quad q) holds m = kb*32 + q*8 + 0..7 for its n-col.
            // p32swap: X=[Xq0,Xq1,Yq0,Yq1], Y=[Xq2,Xq3,Yq2,Yq3];
            // p16swap: X=[Xq0,Xq2,Yq0,Yq2]=T[d], Y=[Xq1,Xq3,Yq1,Yq3]=T[d+2].
            half8v pa[2];
            #pragma unroll
            for (int nj = 0; nj < 2; ++nj) {
                unsigned T[4];
                #pragma unroll
                for (int d = 0; d < 2; ++d) {
                    unsigned X = pk[0][nj][d], Y = pk[1][nj][d];
                    asm("v_permlane32_swap_b32 %0, %1" : "+v"(X), "+v"(Y));
                    asm("v_permlane16_swap_b32 %0, %1" : "+v"(X), "+v"(Y));
                    T[d]     = X;
                    T[d + 2] = Y;
                }
                uint4v tv = {T[0], T[1], T[2], T[3]};
                pa[nj] = __builtin_bit_cast(half8v, tv);
            }
            __builtin_amdgcn_s_setprio(1);
            #pragma unroll
            for (int cj = 0; cj < 4; ++cj) {
                half8v ab = *(half8v*)&lb[(cj * 16 + l16) * 64 + ((kb * 32 + quad * 8) ^ rsw)];
                pv[cj][0] = __builtin_amdgcn_mfma_f32_16x16x32_f16(ab, pa[0], pv[cj][0], 0, 0, 0);
                pv[cj][1] = __builtin_amdgcn_mfma_f32_16x16x32_f16(ab, pa[1], pv[cj][1], 0, 0, 0);
            }
            __builtin_amdgcn_s_setprio(0);
        }
    }
    for (int o2 = 32; o2; o2 >>= 1) zacc += __shfl_xor(zacc, o2, 64);
    if (lane == 0) {
        ws[msoOff + s * 512 + b * 128 + st * 4 + w] = runm;
        ws[zsoOff + s * 512 + b * 128 + st * 4 + w] = zacc;
    }
    // O^T frags -> PV[n][c] bf16, coalesced 8B stores (4 consecutive c per lane)
    short* pvp = (short*)(ws + PVO) + (size_t)s * 1048576 + (size_t)b * IMG;
    #pragma unroll
    for (int cj = 0; cj < 4; ++cj)
        #pragma unroll
        for (int nj = 0; nj < 2; ++nj) {
            short4v o;
            #pragma unroll
            for (int r = 0; r < 4; ++r) o[r] = f2bf(pv[cj][nj][r]);
            *(short4v*)&pvp[(size_t)(n0 + w * 32 + nj * 16 + l16) * 64 + cj * 16 + quad * 4] = o;
        }
}

// ---- Dispatch 4: inline M/Z reduction + u = x + softmax@bottom (short8 PV reads)
// + u-powers -> chunked padded fp16. 512 threads/block.
__global__ __launch_bounds__(512) void k_finalu(const float* __restrict__ x, float* __restrict__ ws,
                                                _Float16* __restrict__ upad,
                                                int ms, int msoOff, int zsoOff) {
    __shared__ float us[64 * 65];
    __shared__ float rm[8], rz[8];
    int t = threadIdx.x, bx = blockIdx.x;
    int b = bx >> 6, h = bx & 63;
    int g = t & 127;   // group index (duplicated across t>=128; z guarded)
    float m = -3.0e38f;
    for (int s = 0; s < ms; ++s)
        m = fmaxf(m, ws[msoOff + s * 512 + b * 128 + g]);
    for (int o2 = 32; o2; o2 >>= 1) m = fmaxf(m, __shfl_xor(m, o2, 64));
    if ((t & 63) == 0) rm[t >> 6] = m;
    __syncthreads();
    float M = rm[0];
    #pragma unroll
    for (int j = 1; j < 8; ++j) M = fmaxf(M, rm[j]);
    float z = 0.f;
    if (t < 128) {
        for (int s = 0; s < ms; ++s)
            z += ws[zsoOff + s * 512 + b * 128 + g] *
                 __builtin_amdgcn_exp2f(ws[msoOff + s * 512 + b * 128 + g] - M);
    }
    for (int o2 = 32; o2; o2 >>= 1) z += __shfl_xor(z, o2, 64);
    if ((t & 63) == 0) rz[t >> 6] = z;
    __syncthreads();
    float Z = 0.f;
    #pragma unroll
    for (int j = 0; j < 8; ++j) Z += rz[j];
    float rZ = 1.0f / Z;

    const short* pvb = (const short*)(ws + PVO) + (size_t)b * IMG;
    int hg = h >> 5;
    {
        int idx = t * 8;                  // 512 threads x 8 = 4096 elems exact
        int ci = idx >> 6, wc = idx & 63;
        int rem = ci * 4096 + h * 64 + wc;
        int grp = ci * 2 + hg;            // n = ci*64+h; 32-row group = n>>5
        float acc[8] = {};
        for (int s = 0; s < ms; ++s) {
            float scl = __builtin_amdgcn_exp2f(ws[msoOff + s * 512 + b * 128 + grp] - M);
            short8v pvv = *(const short8v*)&pvb[(size_t)s * 1048576 + rem];
            #pragma unroll
            for (int i = 0; i < 8; ++i) acc[i] += bf2f(pvv[i]) * scl;
        }
        float4 x0 = *(const float4*)&x[(size_t)b * IMG + rem];
        float4 x1 = *(const float4*)&x[(size_t)b * IMG + rem + 4];
        float xv[8] = {x0.x, x0.y, x0.z, x0.w, x1.x, x1.y, x1.z, x1.w};
        #pragma unroll
        for (int i = 0; i < 8; ++i)
            us[ci * 65 + wc + i] = xv[i] + acc[i] * rZ;
    }
    __syncthreads();
    _Float16* dst = upad + ((size_t)b * 6 * PADIMG + (h + 1) * 66 + 1) * 32;
    #pragma unroll
    for (int it = 0; it < 3; ++it) {
        int u = it * 512 + t;             // 1536 units
        int ck = u >> 8, within = u & 255;
        int px = within >> 2, q = within & 3;
        int k0 = ck * 32 + q * 8;
        int p = k0 >> 6, c0 = k0 & 63;
        half8v o;
        #pragma unroll
        for (int j = 0; j < 8; ++j) {
            float v = us[(c0 + j) * 65 + px];
            float pw = (p == 0) ? v : ((p == 1) ? v * v : v * v * v);
            o[j] = (_Float16)pw;
        }
        *(half8v*)&dst[((size_t)ck * PADIMG + px) * 32 + q * 8] = o;
    }
}

// ---- Dispatch 5: final 3x3 conv, direct fp32 output + bias, oc-32. grid 512.
__global__ __launch_bounds__(256) void k_conv3o(const _Float16* __restrict__ upad,
                                                const _Float16* __restrict__ wout,
                                                const float* __restrict__ ob,
                                                float* __restrict__ out) {
    conv3d32(blockIdx.x, threadIdx.x, upad, wout, ob, nullptr, out);
}

extern "C" void kernel_launch(void* const* d_in, const int* in_sizes, int n_in,
                              void* d_out, int out_size, void* d_ws, size_t ws_size,
                              hipStream_t stream) {
    (void)in_sizes; (void)n_in; (void)out_size;
    const float* x  = (const float*)d_in[0];
    const float* tw = (const float*)d_in[1];
    const float* tb = (const float*)d_in[2];
    const float* cw = (const float*)d_in[3];
    const float* cb = (const float*)d_in[4];
    const float* bw = (const float*)d_in[5];
    const float* bb = (const float*)d_in[6];
    const float* ow = (const float*)d_in[7];
    const float* ob = (const float*)d_in[8];
    float* ws  = (float*)d_ws;
    float* out = (float*)d_out;

    _Float16* wbf  = (_Float16*)(ws + WBFO);
    _Float16* wout = wbf + 110592;
    _Float16* xpad = (_Float16*)(ws + XPADO);   // also upad (aliased)
    _Float16* topb = (_Float16*)(ws + TOPO);
    _Float16* cenb = (_Float16*)(ws + CENO);
    _Float16* botb = (_Float16*)(ws + BOTO);

    // m-split count: 8 (grid 1024) when the workspace can hold the 16MB PV
    // buffer; otherwise fall back to the proven 4-split layout.
    int ms     = (ws_size >= NEED8) ? 8 : 4;
    int msoOff = (ms == 8) ? MSO8 : MSO4;
    int zsoOff = msoOff + ms * 512;

    hipLaunchKernelGGL(k_prep, dim3(1216), dim3(256), 0, stream, bw, ow, tw, cw, wbf, x, xpad);
    hipLaunchKernelGGL(k_convs, dim3(1024), dim3(256), 0, stream, xpad, wbf, tb, cb, bb, topb, cenb, botb);
    if (ms == 8)
        hipLaunchKernelGGL(k_attn<8>,  dim3(1024), dim3(256), 0, stream, ws, msoOff, zsoOff);
    else
        hipLaunchKernelGGL(k_attn<16>, dim3(512),  dim3(256), 0, stream, ws, msoOff, zsoOff);
    hipLaunchKernelGGL(k_finalu, dim3(256), dim3(512), 0, stream, x, ws, xpad, ms, msoOff, zsoOff);
    hipLaunchKernelGGL(k_conv3o, dim3(512), dim3(256), 0, stream, xpad, wout, ob, out);
}

// Round 11
// 153.567 us; speedup vs baseline: 1.0390x; 1.0390x over previous
//
#include <hip/hip_runtime.h>
#include <hip/hip_bf16.h>

// Problem constants: B=4, C=64, H=W=64, HW=4096, P=64, Q=3 (CQ=192)
namespace {
constexpr int IMG    = 262144;   // 64*4096 elems per batch image
constexpr int PADIMG = 4356;     // 66*66 padded pixels
constexpr float LOG2E = 1.44269504088896340736f;
// workspace float offsets
constexpr int WBFO  = 0;         // fp16 weights: wbot[9][6][64][32], wout[9][6][64][32], wtop[6][64][32], wcen[6][64][32]
constexpr int XPADO = 122880;    // fp16 xp/up padded [b][ck 6][quad 4][px 4356][8] (aliased: xp then up)
constexpr int TOPO  = 1795584;   // fp16 topT [b][m][p]
constexpr int CENO  = 2319872;   // fp16 cenT [b][n][p]
constexpr int BOTO  = 2844160;   // fp16 bot  [b][c][m]
constexpr int PVO   = 3368448;   // bf16 PV [ms][b][n][c]
// M/Z scratch [s][b 4][group 128]: placement depends on m-split count (PV size)
constexpr int MSO4  = 5465600;   // ms=4 legacy layout (PV = 8MB)
constexpr int MSO8  = 7562752;   // ms=8 layout (PV = 16MB)
constexpr size_t NEED8 = (size_t)(MSO8 + 8192) * 4;   // ~30.3 MB workspace for ms=8
}

using half8v  = __attribute__((ext_vector_type(8))) _Float16;
using half4v  = __attribute__((ext_vector_type(4))) _Float16;
using short8v = __attribute__((ext_vector_type(8))) short;
using short4v = __attribute__((ext_vector_type(4))) short;
using uint4v  = __attribute__((ext_vector_type(4))) unsigned;
typedef __attribute__((ext_vector_type(4))) float f32x4;

__device__ __forceinline__ short f2bf(float f) {
    __hip_bfloat16 h = __float2bfloat16(f);
    return *reinterpret_cast<short*>(&h);
}
__device__ __forceinline__ float bf2f(short s) {
    unsigned u = ((unsigned)(unsigned short)s) << 16;
    return __uint_as_float(u);
}
__device__ __forceinline__ unsigned pkrtz(float a, float b) {
    return __builtin_bit_cast(unsigned, __builtin_amdgcn_cvt_pkrtz(a, b));
}
// async global->LDS, 16B/lane. LDS dest is wave-uniform base + lane*16 (m104);
// pass the uniform base, per-lane global src.
__device__ __forceinline__ void gload16(const void* g, void* l) {
    __builtin_amdgcn_global_load_lds(
        (const __attribute__((address_space(1))) unsigned*)g,
        (__attribute__((address_space(3))) unsigned*)l, 16, 0, 0);
}

// ---- Dispatch 1: weights->fp16 reorder into k-chunked layouts (blocks 0..959)
// + x-powers into QUAD-PLANE padded xpad incl. border zeroing (blocks 960..1215).
// R11 layout: xpad element (b, ck, q, px, j) at (((b*24 + ck*4 + q)*PADIMG)+px)*8+j,
// k = ck*32 + q*8 + j. Conv A-loads then read 16 consecutive px * 16B per
// quad-plane -> 4 contiguous 256B segments per wave instruction (was 64x16B
// scattered at stride 64B).
__global__ __launch_bounds__(256) void k_prep(const float* __restrict__ bw, const float* __restrict__ ow,
                                              const float* __restrict__ tw, const float* __restrict__ cw,
                                              _Float16* __restrict__ wbf,
                                              const float* __restrict__ x, _Float16* __restrict__ xpad) {
    __shared__ float xs[64 * 65];
    int bx = blockIdx.x, t = threadIdx.x;
    if (bx < 960) {
        int idx = bx * 256 + t;   // < 245760
        if (idx < 221184) {
            // 3x3: w[o][(p*64+ci)*9+tap] -> wT[tap][ck][o][ki]  (k = ck*32+ki = p*64+ci)
            int tsel = idx / 110592;
            int r    = idx - tsel * 110592;
            int tap  = r / 12288;
            int rr   = r - tap * 12288;
            int ck   = rr / 2048;
            int r2   = rr - ck * 2048;
            int o    = r2 >> 5;
            int ki   = r2 & 31;
            int k    = ck * 32 + ki;
            int p    = k >> 6, ci = k & 63;
            const float* src = tsel ? ow : bw;
            wbf[idx] = (_Float16)src[o * 1728 + (p * 64 + ci) * 9 + tap];
        } else {
            // 1x1: w[o][192] -> wT[ck][o][ki]; center pre-scaled by log2(e)
            int j = idx - 221184;
            int tsel = j / 12288;
            int rr   = j - tsel * 12288;
            int ck   = rr / 2048;
            int r2   = rr - ck * 2048;
            int o    = r2 >> 5;
            int ki   = r2 & 31;
            int k    = ck * 32 + ki;
            wbf[idx] = (_Float16)(tsel ? cw[o * 192 + k] * LOG2E : tw[o * 192 + k]);
        }
        return;
    }
    int bx2 = bx - 960;
    int b = bx2 >> 6, h = bx2 & 63;
    // zero this block's share of the pad border across all 24 quad-planes
    {
        _Float16* base = xpad + (size_t)b * 24 * PADIMG * 8;
        int px[6];
        px[0] = (h + 1) * 66;
        px[1] = (h + 1) * 66 + 65;
        px[2] = h;
        px[3] = 65 * 66 + h;
        int npx = 4;
        if (h < 2) { px[4] = 64 + h; px[5] = 65 * 66 + 64 + h; npx = 6; }
        int pi = t / 24, cpq = t % 24;
        if (pi < npx) {
            half8v z = {0, 0, 0, 0, 0, 0, 0, 0};
            *(half8v*)&base[((size_t)cpq * PADIMG + px[pi]) * 8] = z;
        }
    }
    #pragma unroll
    for (int it = 0; it < 16; ++it) {
        int idx = it * 256 + t;
        int ci = idx >> 6, wc = idx & 63;
        xs[ci * 65 + wc] = x[b * IMG + ci * 4096 + h * 64 + wc];
    }
    __syncthreads();
    _Float16* dst = xpad + ((size_t)b * 24 * PADIMG + (h + 1) * 66 + 1) * 8;
    #pragma unroll
    for (int it = 0; it < 6; ++it) {
        int u = it * 256 + t;
        int ck = u >> 8, within = u & 255;
        int q = within >> 6, px = within & 63;   // px fastest -> contiguous stores
        int k0 = ck * 32 + q * 8;
        int p = k0 >> 6, c0 = k0 & 63;
        half8v o;
        #pragma unroll
        for (int j = 0; j < 8; ++j) {
            float v = xs[(c0 + j) * 65 + px];
            float pw = (p == 0) ? v : ((p == 1) ? v * v : v * v * v);
            o[j] = (_Float16)pw;
        }
        *(half8v*)&dst[((size_t)(ck * 4 + q) * PADIMG + px) * 8] = o;
    }
}

// 3x3 SelfONN conv, full-K MFMA implicit GEMM, 32 oc/block, direct output+bias.
// R11: A-reads from quad-plane xpad -> 4 contiguous 256B segments per load.
__device__ __forceinline__ void conv3d32(int bx, int t,
                                         const _Float16* __restrict__ src,
                                         const _Float16* __restrict__ wt,
                                         const float* __restrict__ bias,
                                         _Float16* __restrict__ dh_, float* __restrict__ df) {
    int lane = t & 63, w = t >> 6;
    int l16 = lane & 15, quad = lane >> 4;
    int oh = bx >> 8, mt = bx & 255;
    int b = mt >> 6, h = mt & 63;
    const _Float16* abase = src + ((size_t)(b * 24 + quad) * PADIMG + (h + 1) * 66 + 1 + w * 16 + l16) * 8;
    const _Float16* bbase = wt + (size_t)(oh * 32 + l16) * 32 + quad * 8;
    f32x4 acc[2];
    acc[0] = (f32x4){0.f, 0.f, 0.f, 0.f};
    acc[1] = (f32x4){0.f, 0.f, 0.f, 0.f};
    #pragma unroll
    for (int tap = 0; tap < 9; ++tap) {
        int dh = tap / 3 - 1, dw = tap % 3 - 1;
        const _Float16* arow = abase + (dh * 66 + dw) * 8;
        const _Float16* brow = bbase + (size_t)tap * 6 * 2048;
        #pragma unroll
        for (int c6 = 0; c6 < 6; ++c6) {
            half8v afr  = *(const half8v*)&arow[(size_t)c6 * 4 * PADIMG * 8];
            half8v bfr0 = *(const half8v*)&brow[(size_t)c6 * 2048];
            half8v bfr1 = *(const half8v*)&brow[(size_t)c6 * 2048 + 512];
            acc[0] = __builtin_amdgcn_mfma_f32_16x16x32_f16(afr, bfr0, acc[0], 0, 0, 0);
            acc[1] = __builtin_amdgcn_mfma_f32_16x16x32_f16(afr, bfr1, acc[1], 0, 0, 0);
        }
    }
    #pragma unroll
    for (int nf = 0; nf < 2; ++nf) {
        int c = oh * 32 + nf * 16 + l16;
        float bv = bias[c];
        size_t oi = (size_t)b * 262144 + (size_t)c * 4096 + h * 64 + w * 16 + quad * 4;
        if (dh_) {
            half4v o;
            #pragma unroll
            for (int r = 0; r < 4; ++r) o[r] = (_Float16)(acc[nf][r] + bv);
            *(half4v*)&dh_[oi] = o;
        } else {
            float4 o = make_float4(acc[nf][0] + bv, acc[nf][1] + bv, acc[nf][2] + bv, acc[nf][3] + bv);
            *(float4*)&df[oi] = o;
        }
    }
}

// ---- Dispatch 2: conv3-bottom (blocks 0..511, direct fp16 out, oc-32) + fused
// top/center 1x1 convs (blocks 512..1023).
__global__ __launch_bounds__(256) void k_convs(const _Float16* __restrict__ xpad,
                                               const _Float16* __restrict__ wbf,
                                               const float* __restrict__ tb, const float* __restrict__ cb,
                                               const float* __restrict__ bbias,
                                               _Float16* __restrict__ topd, _Float16* __restrict__ cend,
                                               _Float16* __restrict__ botb) {
    int bx = blockIdx.x, t = threadIdx.x;
    if (bx < 512) {
        conv3d32(bx, t, xpad, wbf /* wbot at offset 0 */, bbias, botb, nullptr);
        return;
    }
    int bx2 = bx - 512;
    int lane = t & 63, w = t >> 6;
    int l16 = lane & 15, quad = lane >> 4;
    int ot = bx2 >> 8, mt = bx2 & 255;
    int b = mt >> 6, h = mt & 63;
    const _Float16* wt   = wbf + (ot ? 233472 : 221184);   // wcen : wtop
    const float*    bias = ot ? cb : tb;
    _Float16*       dst  = (ot ? cend : topd) + (size_t)b * IMG;
    const _Float16* abase = xpad + ((size_t)(b * 24 + quad) * PADIMG + (h + 1) * 66 + 1 + w * 16 + l16) * 8;
    const _Float16* bbase = wt + (size_t)l16 * 32 + quad * 8;
    f32x4 acc[4];
    #pragma unroll
    for (int nf = 0; nf < 4; ++nf) acc[nf] = (f32x4){0.f, 0.f, 0.f, 0.f};
    #pragma unroll
    for (int kc = 0; kc < 6; ++kc) {
        half8v afr = *(const half8v*)&abase[(size_t)kc * 4 * PADIMG * 8];
        #pragma unroll
        for (int nf = 0; nf < 4; ++nf) {
            half8v bfr = *(const half8v*)&bbase[(size_t)kc * 2048 + nf * 16 * 32];
            acc[nf] = __builtin_amdgcn_mfma_f32_16x16x32_f16(afr, bfr, acc[nf], 0, 0, 0);
        }
    }
    _Float16* dp = dst + (size_t)(h * 64 + w * 16) * 64;
    #pragma unroll
    for (int nf = 0; nf < 4; ++nf) {
        float bv = bias[nf * 16 + l16];
        if (ot) bv *= LOG2E;   // center output lives in log2e-scaled domain
        #pragma unroll
        for (int r = 0; r < 4; ++r)
            dp[(quad * 4 + r) * 64 + nf * 16 + l16] = (_Float16)(acc[nf][r] + bv);
    }
}

// ---- Dispatch 3: fp16 MFMA flash attention, global softmax (unchanged from R10:
// launch_bounds(256,4), gload_lds staging with pre-swizzled source, XOR-swizzled
// unpadded LDS, in-reg P via permlane32+16 exchange, defer-max, 1 barrier/tile).
template<int MT>
__global__ __launch_bounds__(256, 4) void k_attn(float* __restrict__ ws, int msoOff, int zsoOff) {
    __shared__ _Float16 ltop[2][64 * 64];    // [buf][m][p swizzled]
    __shared__ _Float16 lbot[2][64 * 64];    // [buf][c][m swizzled]
    int t    = threadIdx.x;
    int lane = t & 63, w = t >> 6;
    int l16  = lane & 15, quad = lane >> 4;
    int bxr = blockIdx.x;
    int bx  = (bxr & 7) * ((int)gridDim.x >> 3) + (bxr >> 3);
    int st = bx & 31, b = (bx >> 5) & 3, s = bx >> 7;
    int n0 = st * 128;
    int mbase = s * MT * 64;
    const _Float16* topg = (const _Float16*)(ws + TOPO) + (size_t)b * IMG;
    const _Float16* ceng = (const _Float16*)(ws + CENO) + (size_t)b * IMG;
    const _Float16* botg = (const _Float16*)(ws + BOTO) + (size_t)b * IMG;

    int r0   = t >> 3;                       // 0..31 (and +32 for 2nd half)
    int swz0 = ((t & 7) ^ (r0 & 7)) * 8;     // halves
    int rsw  = (l16 & 7) * 8;                // read-side XOR (halves)

    auto stage = [&](int buf, int mt) {
        gload16(topg + (size_t)(mt + r0) * 64 + swz0,      &ltop[buf][w * 512]);
        gload16(topg + (size_t)(mt + r0 + 32) * 64 + swz0, &ltop[buf][2048 + w * 512]);
        gload16(botg + (size_t)r0 * 4096 + mt + swz0,      &lbot[buf][w * 512]);
        gload16(botg + (size_t)(r0 + 32) * 4096 + mt + swz0, &lbot[buf][2048 + w * 512]);
    };

    // B-frag of QK^T: cen, register-resident. lane l16 = n-col, quad*8 = k(p)
    half8v bcen[2][2];   // [nj][kk]
    #pragma unroll
    for (int nj = 0; nj < 2; ++nj)
        #pragma unroll
        for (int kk = 0; kk < 2; ++kk)
            bcen[nj][kk] = *(const half8v*)&ceng[(size_t)(n0 + w * 32 + nj * 16 + l16) * 64 + kk * 32 + quad * 8];

    f32x4 pv[4][2];   // O^T frags: [cj][nj], row c = cj*16+quad*4+r, col n = nj*16+l16
    #pragma unroll
    for (int cj = 0; cj < 4; ++cj)
        #pragma unroll
        for (int nj = 0; nj < 2; ++nj) pv[cj][nj] = (f32x4){0.f, 0.f, 0.f, 0.f};
    float runm = -3.0e38f, zacc = 0.f;

    stage(0, mbase);

    #pragma unroll
    for (int tt = 0; tt < MT; ++tt) {
        const _Float16* lt = ltop[tt & 1];
        const _Float16* lb = lbot[tt & 1];
        __syncthreads();   // drains this wave's gloads; prev compute done block-wide
        if (tt + 1 < MT) stage((tt + 1) & 1, mbase + (tt + 1) * 64);
        // S^T = top * cen^T: sa[mi][nj], row m = mi*16+quad*4+r, col n = nj*16+l16
        f32x4 sa[4][2];
        #pragma unroll
        for (int mi = 0; mi < 4; ++mi)
            #pragma unroll
            for (int nj = 0; nj < 2; ++nj) sa[mi][nj] = (f32x4){0.f, 0.f, 0.f, 0.f};
        __builtin_amdgcn_s_setprio(1);
        #pragma unroll
        for (int kk = 0; kk < 2; ++kk)
            #pragma unroll
            for (int mi = 0; mi < 4; ++mi) {
                half8v at = *(half8v*)&lt[(mi * 16 + l16) * 64 + ((kk * 32 + quad * 8) ^ rsw)];
                sa[mi][0] = __builtin_amdgcn_mfma_f32_16x16x32_f16(at, bcen[0][kk], sa[mi][0], 0, 0, 0);
                sa[mi][1] = __builtin_amdgcn_mfma_f32_16x16x32_f16(at, bcen[1][kk], sa[mi][1], 0, 0, 0);
            }
        __builtin_amdgcn_s_setprio(0);
        // lane-local tile max
        float lm = -3.0e38f;
        #pragma unroll
        for (int mi = 0; mi < 4; ++mi)
            #pragma unroll
            for (int nj = 0; nj < 2; ++nj) {
                float a  = fmaxf(sa[mi][nj][0], sa[mi][nj][1]);
                float c2 = fmaxf(sa[mi][nj][2], sa[mi][nj][3]);
                lm = fmaxf(lm, fmaxf(a, c2));
            }
        // T13 defer-max: only reduce+rescale when some lane exceeds runm+8
        if (!__all(lm - runm <= 8.0f)) {
            float tm = lm;
            for (int o2 = 32; o2; o2 >>= 1) tm = fmaxf(tm, __shfl_xor(tm, o2, 64));
            if (tm > runm) {
                float sc = __builtin_amdgcn_exp2f(runm - tm);
                zacc *= sc;
                #pragma unroll
                for (int cj = 0; cj < 4; ++cj)
                    #pragma unroll
                    for (int nj = 0; nj < 2; ++nj) pv[cj][nj] *= sc;
                runm = tm;
            }
        }
        // Per kb (32-m half): exp2 -> fp16 pack -> pure-VALU quad exchange -> PV
        #pragma unroll
        for (int kb = 0; kb < 2; ++kb) {
            unsigned pk[2][2][2];   // [f = mi&1][nj][d]
            #pragma unroll
            for (int f = 0; f < 2; ++f) {
                int mi = 2 * kb + f;
                #pragma unroll
                for (int nj = 0; nj < 2; ++nj) {
                    float e0 = __builtin_amdgcn_exp2f(sa[mi][nj][0] - runm);
                    float e1 = __builtin_amdgcn_exp2f(sa[mi][nj][1] - runm);
                    float e2 = __builtin_amdgcn_exp2f(sa[mi][nj][2] - runm);
                    float e3 = __builtin_amdgcn_exp2f(sa[mi][nj][3] - runm);
                    zacc += (e0 + e1) + (e2 + e3);
                    pk[f][nj][0] = pkrtz(e0, e1);
                    pk[f][nj][1] = pkrtz(e2, e3);
                }
            }
            // Exchange: dst lane(quad q) holds m = kb*32 + q*8 + 0..7 for its n-col.
            // p32swap: X=[Xq0,Xq1,Yq0,Yq1], Y=[Xq2,Xq3,Yq2,Yq3];
            // p16swap: X=[Xq0,Xq2,Yq0,Yq2]=T[d], Y=[Xq1,Xq3,Yq1,Yq3]=T[d+2].
            half8v pa[2];
            #pragma unroll
            for (int nj = 0; nj < 2; ++nj) {
                unsigned T[4];
                #pragma unroll
                for (int d = 0; d < 2; ++d) {
                    unsigned X = pk[0][nj][d], Y = pk[1][nj][d];
                    asm("v_permlane32_swap_b32 %0, %1" : "+v"(X), "+v"(Y));
                    asm("v_permlane16_swap_b32 %0, %1" : "+v"(X), "+v"(Y));
                    T[d]     = X;
                    T[d + 2] = Y;
                }
                uint4v tv = {T[0], T[1], T[2], T[3]};
                pa[nj] = __builtin_bit_cast(half8v, tv);
            }
            __builtin_amdgcn_s_setprio(1);
            #pragma unroll
            for (int cj = 0; cj < 4; ++cj) {
                half8v ab = *(half8v*)&lb[(cj * 16 + l16) * 64 + ((kb * 32 + quad * 8) ^ rsw)];
                pv[cj][0] = __builtin_amdgcn_mfma_f32_16x16x32_f16(ab, pa[0], pv[cj][0], 0, 0, 0);
                pv[cj][1] = __builtin_amdgcn_mfma_f32_16x16x32_f16(ab, pa[1], pv[cj][1], 0, 0, 0);
            }
            __builtin_amdgcn_s_setprio(0);
        }
    }
    for (int o2 = 32; o2; o2 >>= 1) zacc += __shfl_xor(zacc, o2, 64);
    if (lane == 0) {
        ws[msoOff + s * 512 + b * 128 + st * 4 + w] = runm;
        ws[zsoOff + s * 512 + b * 128 + st * 4 + w] = zacc;
    }
    // O^T frags -> PV[n][c] bf16, coalesced 8B stores (4 consecutive c per lane)
    short* pvp = (short*)(ws + PVO) + (size_t)s * 1048576 + (size_t)b * IMG;
    #pragma unroll
    for (int cj = 0; cj < 4; ++cj)
        #pragma unroll
        for (int nj = 0; nj < 2; ++nj) {
            short4v o;
            #pragma unroll
            for (int r = 0; r < 4; ++r) o[r] = f2bf(pv[cj][nj][r]);
            *(short4v*)&pvp[(size_t)(n0 + w * 32 + nj * 16 + l16) * 64 + cj * 16 + quad * 4] = o;
        }
}

// ---- Dispatch 4: inline M/Z reduction + u = x + softmax@bottom (short8 PV reads)
// + u-powers -> quad-plane padded fp16. 512 threads/block.
__global__ __launch_bounds__(512) void k_finalu(const float* __restrict__ x, float* __restrict__ ws,
                                                _Float16* __restrict__ upad,
                                                int ms, int msoOff, int zsoOff) {
    __shared__ float us[64 * 65];
    __shared__ float rm[8], rz[8];
    int t = threadIdx.x, bx = blockIdx.x;
    int b = bx >> 6, h = bx & 63;
    int g = t & 127;   // group index (duplicated across t>=128; z guarded)
    float m = -3.0e38f;
    for (int s = 0; s < ms; ++s)
        m = fmaxf(m, ws[msoOff + s * 512 + b * 128 + g]);
    for (int o2 = 32; o2; o2 >>= 1) m = fmaxf(m, __shfl_xor(m, o2, 64));
    if ((t & 63) == 0) rm[t >> 6] = m;
    __syncthreads();
    float M = rm[0];
    #pragma unroll
    for (int j = 1; j < 8; ++j) M = fmaxf(M, rm[j]);
    float z = 0.f;
    if (t < 128) {
        for (int s = 0; s < ms; ++s)
            z += ws[zsoOff + s * 512 + b * 128 + g] *
                 __builtin_amdgcn_exp2f(ws[msoOff + s * 512 + b * 128 + g] - M);
    }
    for (int o2 = 32; o2; o2 >>= 1) z += __shfl_xor(z, o2, 64);
    if ((t & 63) == 0) rz[t >> 6] = z;
    __syncthreads();
    float Z = 0.f;
    #pragma unroll
    for (int j = 0; j < 8; ++j) Z += rz[j];
    float rZ = 1.0f / Z;

    const short* pvb = (const short*)(ws + PVO) + (size_t)b * IMG;
    int hg = h >> 5;
    {
        int idx = t * 8;                  // 512 threads x 8 = 4096 elems exact
        int ci = idx >> 6, wc = idx & 63;
        int rem = ci * 4096 + h * 64 + wc;
        int grp = ci * 2 + hg;            // n = ci*64+h; 32-row group = n>>5
        float acc[8] = {};
        for (int s = 0; s < ms; ++s) {
            float scl = __builtin_amdgcn_exp2f(ws[msoOff + s * 512 + b * 128 + grp] - M);
            short8v pvv = *(const short8v*)&pvb[(size_t)s * 1048576 + rem];
            #pragma unroll
            for (int i = 0; i < 8; ++i) acc[i] += bf2f(pvv[i]) * scl;
        }
        float4 x0 = *(const float4*)&x[(size_t)b * IMG + rem];
        float4 x1 = *(const float4*)&x[(size_t)b * IMG + rem + 4];
        float xv[8] = {x0.x, x0.y, x0.z, x0.w, x1.x, x1.y, x1.z, x1.w};
        #pragma unroll
        for (int i = 0; i < 8; ++i)
            us[ci * 65 + wc + i] = xv[i] + acc[i] * rZ;
    }
    __syncthreads();
    _Float16* dst = upad + ((size_t)b * 24 * PADIMG + (h + 1) * 66 + 1) * 8;
    #pragma unroll
    for (int it = 0; it < 3; ++it) {
        int u = it * 512 + t;             // 1536 units
        int ck = u >> 8, within = u & 255;
        int q = within >> 6, px = within & 63;   // px fastest -> contiguous stores
        int k0 = ck * 32 + q * 8;
        int p = k0 >> 6, c0 = k0 & 63;
        half8v o;
        #pragma unroll
        for (int j = 0; j < 8; ++j) {
            float v = us[(c0 + j) * 65 + px];
            float pw = (p == 0) ? v : ((p == 1) ? v * v : v * v * v);
            o[j] = (_Float16)pw;
        }
        *(half8v*)&dst[((size_t)(ck * 4 + q) * PADIMG + px) * 8] = o;
    }
}

// ---- Dispatch 5: final 3x3 conv, direct fp32 output + bias, oc-32. grid 512.
__global__ __launch_bounds__(256) void k_conv3o(const _Float16* __restrict__ upad,
                                                const _Float16* __restrict__ wout,
                                                const float* __restrict__ ob,
                                                float* __restrict__ out) {
    conv3d32(blockIdx.x, threadIdx.x, upad, wout, ob, nullptr, out);
}

extern "C" void kernel_launch(void* const* d_in, const int* in_sizes, int n_in,
                              void* d_out, int out_size, void* d_ws, size_t ws_size,
                              hipStream_t stream) {
    (void)in_sizes; (void)n_in; (void)out_size;
    const float* x  = (const float*)d_in[0];
    const float* tw = (const float*)d_in[1];
    const float* tb = (const float*)d_in[2];
    const float* cw = (const float*)d_in[3];
    const float* cb = (const float*)d_in[4];
    const float* bw = (const float*)d_in[5];
    const float* bb = (const float*)d_in[6];
    const float* ow = (const float*)d_in[7];
    const float* ob = (const float*)d_in[8];
    float* ws  = (float*)d_ws;
    float* out = (float*)d_out;

    _Float16* wbf  = (_Float16*)(ws + WBFO);
    _Float16* wout = wbf + 110592;
    _Float16* xpad = (_Float16*)(ws + XPADO);   // also upad (aliased)
    _Float16* topb = (_Float16*)(ws + TOPO);
    _Float16* cenb = (_Float16*)(ws + CENO);
    _Float16* botb = (_Float16*)(ws + BOTO);

    // m-split count: 8 (grid 1024) when the workspace can hold the 16MB PV
    // buffer; otherwise fall back to the proven 4-split layout.
    int ms     = (ws_size >= NEED8) ? 8 : 4;
    int msoOff = (ms == 8) ? MSO8 : MSO4;
    int zsoOff = msoOff + ms * 512;

    hipLaunchKernelGGL(k_prep, dim3(1216), dim3(256), 0, stream, bw, ow, tw, cw, wbf, x, xpad);
    hipLaunchKernelGGL(k_convs, dim3(1024), dim3(256), 0, stream, xpad, wbf, tb, cb, bb, topb, cenb, botb);
    if (ms == 8)
        hipLaunchKernelGGL(k_attn<8>,  dim3(1024), dim3(256), 0, stream, ws, msoOff, zsoOff);
    else
        hipLaunchKernelGGL(k_attn<16>, dim3(512),  dim3(256), 0, stream, ws, msoOff, zsoOff);
    hipLaunchKernelGGL(k_finalu, dim3(256), dim3(512), 0, stream, x, ws, xpad, ms, msoOff, zsoOff);
    hipLaunchKernelGGL(k_conv3o, dim3(512), dim3(256), 0, stream, xpad, wout, ob, out);
}

// Round 12
// 142.699 us; speedup vs baseline: 1.1181x; 1.0762x over previous
//
#include <hip/hip_runtime.h>
#include <hip/hip_bf16.h>

// Problem constants: B=4, C=64, H=W=64, HW=4096, P=64, Q=3 (CQ=192)
namespace {
constexpr int IMG    = 262144;   // 64*4096 elems per batch image
constexpr int PADIMG = 4356;     // 66*66 padded pixels
constexpr float LOG2E = 1.44269504088896340736f;
// workspace float offsets
constexpr int WBFO  = 0;         // fp16 weights, quad-plane: w[tap][ck][q][o][8]
constexpr int XPADO = 122880;    // fp16 xp/up padded [b][ck 6][quad 4][px 4356][8] (aliased: xp then up)
constexpr int TOPO  = 1795584;   // fp16 topT [b][m][p]
constexpr int CENO  = 2319872;   // fp16 cenT [b][n][p]
constexpr int BOTO  = 2844160;   // fp16 bot  [b][c][m]
constexpr int PVO   = 3368448;   // bf16 PV [ms][b][n][c]
// M/Z scratch [s][b 4][group 128]: placement depends on m-split count (PV size)
constexpr int MSO4  = 5465600;   // ms=4 legacy layout (PV = 8MB)
constexpr int MSO8  = 7562752;   // ms=8 layout (PV = 16MB)
constexpr size_t NEED8 = (size_t)(MSO8 + 8192) * 4;   // ~30.3 MB workspace for ms=8
}

using half8v  = __attribute__((ext_vector_type(8))) _Float16;
using half4v  = __attribute__((ext_vector_type(4))) _Float16;
using short8v = __attribute__((ext_vector_type(8))) short;
using short4v = __attribute__((ext_vector_type(4))) short;
using uint4v  = __attribute__((ext_vector_type(4))) unsigned;
typedef __attribute__((ext_vector_type(4))) float f32x4;

__device__ __forceinline__ short f2bf(float f) {
    __hip_bfloat16 h = __float2bfloat16(f);
    return *reinterpret_cast<short*>(&h);
}
__device__ __forceinline__ float bf2f(short s) {
    unsigned u = ((unsigned)(unsigned short)s) << 16;
    return __uint_as_float(u);
}
__device__ __forceinline__ unsigned pkrtz(float a, float b) {
    return __builtin_bit_cast(unsigned, __builtin_amdgcn_cvt_pkrtz(a, b));
}
// async global->LDS, 16B/lane. LDS dest is wave-uniform base + lane*16 (m104);
// pass the uniform base, per-lane global src.
__device__ __forceinline__ void gload16(const void* g, void* l) {
    __builtin_amdgcn_global_load_lds(
        (const __attribute__((address_space(1))) unsigned*)g,
        (__attribute__((address_space(3))) unsigned*)l, 16, 0, 0);
}

// ---- Dispatch 1: weights->fp16 reorder into QUAD-PLANE k-chunked layouts
// (blocks 0..959) + x-powers into quad-plane padded xpad incl. border zeroing
// (blocks 960..1215).
// R12 weight layout: w[tap][ck][q][o][j] at tap*12288 + ck*2048 + q*512 + o*8 + j,
// k = ck*32 + q*8 + j (1x1: same without tap). Conv B-loads then read one 256B
// contiguous segment per 16-lane quad (was 16 scattered 64B lines).
__global__ __launch_bounds__(256) void k_prep(const float* __restrict__ bw, const float* __restrict__ ow,
                                              const float* __restrict__ tw, const float* __restrict__ cw,
                                              _Float16* __restrict__ wbf,
                                              const float* __restrict__ x, _Float16* __restrict__ xpad) {
    __shared__ float xs[64 * 65];
    int bx = blockIdx.x, t = threadIdx.x;
    if (bx < 960) {
        int idx = bx * 256 + t;   // < 245760
        if (idx < 221184) {
            // 3x3: w[o][(p*64+ci)*9+tap] -> wT[tap][ck][q][o][j]
            int tsel = idx / 110592;
            int r    = idx - tsel * 110592;
            int tap  = r / 12288;
            int rr   = r - tap * 12288;
            int ck   = rr / 2048;
            int r2   = rr - ck * 2048;
            int q    = r2 >> 9;
            int o    = (r2 >> 3) & 63;
            int j    = r2 & 7;
            int k    = ck * 32 + q * 8 + j;
            int p    = k >> 6, ci = k & 63;
            const float* src = tsel ? ow : bw;
            wbf[idx] = (_Float16)src[o * 1728 + (p * 64 + ci) * 9 + tap];
        } else {
            // 1x1: w[o][192] -> wT[ck][q][o][j]; center pre-scaled by log2(e)
            int jx = idx - 221184;
            int tsel = jx / 12288;
            int rr   = jx - tsel * 12288;
            int ck   = rr / 2048;
            int r2   = rr - ck * 2048;
            int q    = r2 >> 9;
            int o    = (r2 >> 3) & 63;
            int j    = r2 & 7;
            int k    = ck * 32 + q * 8 + j;
            wbf[idx] = (_Float16)(tsel ? cw[o * 192 + k] * LOG2E : tw[o * 192 + k]);
        }
        return;
    }
    int bx2 = bx - 960;
    int b = bx2 >> 6, h = bx2 & 63;
    // zero this block's share of the pad border across all 24 quad-planes
    {
        _Float16* base = xpad + (size_t)b * 24 * PADIMG * 8;
        int px[6];
        px[0] = (h + 1) * 66;
        px[1] = (h + 1) * 66 + 65;
        px[2] = h;
        px[3] = 65 * 66 + h;
        int npx = 4;
        if (h < 2) { px[4] = 64 + h; px[5] = 65 * 66 + 64 + h; npx = 6; }
        int pi = t / 24, cpq = t % 24;
        if (pi < npx) {
            half8v z = {0, 0, 0, 0, 0, 0, 0, 0};
            *(half8v*)&base[((size_t)cpq * PADIMG + px[pi]) * 8] = z;
        }
    }
    #pragma unroll
    for (int it = 0; it < 16; ++it) {
        int idx = it * 256 + t;
        int ci = idx >> 6, wc = idx & 63;
        xs[ci * 65 + wc] = x[b * IMG + ci * 4096 + h * 64 + wc];
    }
    __syncthreads();
    _Float16* dst = xpad + ((size_t)b * 24 * PADIMG + (h + 1) * 66 + 1) * 8;
    #pragma unroll
    for (int it = 0; it < 6; ++it) {
        int u = it * 256 + t;
        int ck = u >> 8, within = u & 255;
        int q = within >> 6, px = within & 63;   // px fastest -> contiguous stores
        int k0 = ck * 32 + q * 8;
        int p = k0 >> 6, c0 = k0 & 63;
        half8v o;
        #pragma unroll
        for (int j = 0; j < 8; ++j) {
            float v = xs[(c0 + j) * 65 + px];
            float pw = (p == 0) ? v : ((p == 1) ? v * v : v * v * v);
            o[j] = (_Float16)pw;
        }
        *(half8v*)&dst[((size_t)(ck * 4 + q) * PADIMG + px) * 8] = o;
    }
}

// 3x3 SelfONN conv, full-K MFMA implicit GEMM, 32 oc/block, direct output+bias.
// R12: A-reads (quad-plane xpad) AND B-reads (quad-plane weights) are 256B/quad
// contiguous.
__device__ __forceinline__ void conv3d32(int bx, int t,
                                         const _Float16* __restrict__ src,
                                         const _Float16* __restrict__ wt,
                                         const float* __restrict__ bias,
                                         _Float16* __restrict__ dh_, float* __restrict__ df) {
    int lane = t & 63, w = t >> 6;
    int l16 = lane & 15, quad = lane >> 4;
    int oh = bx >> 8, mt = bx & 255;
    int b = mt >> 6, h = mt & 63;
    const _Float16* abase = src + ((size_t)(b * 24 + quad) * PADIMG + (h + 1) * 66 + 1 + w * 16 + l16) * 8;
    const _Float16* bbase = wt + (size_t)(oh * 32 + l16) * 8 + quad * 512;
    f32x4 acc[2];
    acc[0] = (f32x4){0.f, 0.f, 0.f, 0.f};
    acc[1] = (f32x4){0.f, 0.f, 0.f, 0.f};
    #pragma unroll
    for (int tap = 0; tap < 9; ++tap) {
        int dh = tap / 3 - 1, dw = tap % 3 - 1;
        const _Float16* arow = abase + (dh * 66 + dw) * 8;
        const _Float16* brow = bbase + (size_t)tap * 12288;
        #pragma unroll
        for (int c6 = 0; c6 < 6; ++c6) {
            half8v afr  = *(const half8v*)&arow[(size_t)c6 * 4 * PADIMG * 8];
            half8v bfr0 = *(const half8v*)&brow[(size_t)c6 * 2048];
            half8v bfr1 = *(const half8v*)&brow[(size_t)c6 * 2048 + 128];
            acc[0] = __builtin_amdgcn_mfma_f32_16x16x32_f16(afr, bfr0, acc[0], 0, 0, 0);
            acc[1] = __builtin_amdgcn_mfma_f32_16x16x32_f16(afr, bfr1, acc[1], 0, 0, 0);
        }
    }
    #pragma unroll
    for (int nf = 0; nf < 2; ++nf) {
        int c = oh * 32 + nf * 16 + l16;
        float bv = bias[c];
        size_t oi = (size_t)b * 262144 + (size_t)c * 4096 + h * 64 + w * 16 + quad * 4;
        if (dh_) {
            half4v o;
            #pragma unroll
            for (int r = 0; r < 4; ++r) o[r] = (_Float16)(acc[nf][r] + bv);
            *(half4v*)&dh_[oi] = o;
        } else {
            float4 o = make_float4(acc[nf][0] + bv, acc[nf][1] + bv, acc[nf][2] + bv, acc[nf][3] + bv);
            *(float4*)&df[oi] = o;
        }
    }
}

// ---- Dispatch 2: conv3-bottom (blocks 0..511, direct fp16 out, oc-32) + fused
// top/center 1x1 convs (blocks 512..1023).
__global__ __launch_bounds__(256) void k_convs(const _Float16* __restrict__ xpad,
                                               const _Float16* __restrict__ wbf,
                                               const float* __restrict__ tb, const float* __restrict__ cb,
                                               const float* __restrict__ bbias,
                                               _Float16* __restrict__ topd, _Float16* __restrict__ cend,
                                               _Float16* __restrict__ botb) {
    int bx = blockIdx.x, t = threadIdx.x;
    if (bx < 512) {
        conv3d32(bx, t, xpad, wbf /* wbot at offset 0 */, bbias, botb, nullptr);
        return;
    }
    int bx2 = bx - 512;
    int lane = t & 63, w = t >> 6;
    int l16 = lane & 15, quad = lane >> 4;
    int ot = bx2 >> 8, mt = bx2 & 255;
    int b = mt >> 6, h = mt & 63;
    const _Float16* wt   = wbf + (ot ? 233472 : 221184);   // wcen : wtop
    const float*    bias = ot ? cb : tb;
    _Float16*       dst  = (ot ? cend : topd) + (size_t)b * IMG;
    const _Float16* abase = xpad + ((size_t)(b * 24 + quad) * PADIMG + (h + 1) * 66 + 1 + w * 16 + l16) * 8;
    const _Float16* bbase = wt + (size_t)l16 * 8 + quad * 512;
    f32x4 acc[4];
    #pragma unroll
    for (int nf = 0; nf < 4; ++nf) acc[nf] = (f32x4){0.f, 0.f, 0.f, 0.f};
    #pragma unroll
    for (int kc = 0; kc < 6; ++kc) {
        half8v afr = *(const half8v*)&abase[(size_t)kc * 4 * PADIMG * 8];
        #pragma unroll
        for (int nf = 0; nf < 4; ++nf) {
            half8v bfr = *(const half8v*)&bbase[(size_t)kc * 2048 + nf * 128];
            acc[nf] = __builtin_amdgcn_mfma_f32_16x16x32_f16(afr, bfr, acc[nf], 0, 0, 0);
        }
    }
    _Float16* dp = dst + (size_t)(h * 64 + w * 16) * 64;
    #pragma unroll
    for (int nf = 0; nf < 4; ++nf) {
        float bv = bias[nf * 16 + l16];
        if (ot) bv *= LOG2E;   // center output lives in log2e-scaled domain
        #pragma unroll
        for (int r = 0; r < 4; ++r)
            dp[(quad * 4 + r) * 64 + nf * 16 + l16] = (_Float16)(acc[nf][r] + bv);
    }
}

// ---- Dispatch 3: fp16 MFMA flash attention, global softmax (unchanged from R10:
// launch_bounds(256,4), gload_lds staging with pre-swizzled source, XOR-swizzled
// unpadded LDS, in-reg P via permlane32+16 exchange, defer-max, 1 barrier/tile).
template<int MT>
__global__ __launch_bounds__(256, 4) void k_attn(float* __restrict__ ws, int msoOff, int zsoOff) {
    __shared__ _Float16 ltop[2][64 * 64];    // [buf][m][p swizzled]
    __shared__ _Float16 lbot[2][64 * 64];    // [buf][c][m swizzled]
    int t    = threadIdx.x;
    int lane = t & 63, w = t >> 6;
    int l16  = lane & 15, quad = lane >> 4;
    int bxr = blockIdx.x;
    int bx  = (bxr & 7) * ((int)gridDim.x >> 3) + (bxr >> 3);
    int st = bx & 31, b = (bx >> 5) & 3, s = bx >> 7;
    int n0 = st * 128;
    int mbase = s * MT * 64;
    const _Float16* topg = (const _Float16*)(ws + TOPO) + (size_t)b * IMG;
    const _Float16* ceng = (const _Float16*)(ws + CENO) + (size_t)b * IMG;
    const _Float16* botg = (const _Float16*)(ws + BOTO) + (size_t)b * IMG;

    int r0   = t >> 3;                       // 0..31 (and +32 for 2nd half)
    int swz0 = ((t & 7) ^ (r0 & 7)) * 8;     // halves
    int rsw  = (l16 & 7) * 8;                // read-side XOR (halves)

    auto stage = [&](int buf, int mt) {
        gload16(topg + (size_t)(mt + r0) * 64 + swz0,      &ltop[buf][w * 512]);
        gload16(topg + (size_t)(mt + r0 + 32) * 64 + swz0, &ltop[buf][2048 + w * 512]);
        gload16(botg + (size_t)r0 * 4096 + mt + swz0,      &lbot[buf][w * 512]);
        gload16(botg + (size_t)(r0 + 32) * 4096 + mt + swz0, &lbot[buf][2048 + w * 512]);
    };

    // B-frag of QK^T: cen, register-resident. lane l16 = n-col, quad*8 = k(p)
    half8v bcen[2][2];   // [nj][kk]
    #pragma unroll
    for (int nj = 0; nj < 2; ++nj)
        #pragma unroll
        for (int kk = 0; kk < 2; ++kk)
            bcen[nj][kk] = *(const half8v*)&ceng[(size_t)(n0 + w * 32 + nj * 16 + l16) * 64 + kk * 32 + quad * 8];

    f32x4 pv[4][2];   // O^T frags: [cj][nj], row c = cj*16+quad*4+r, col n = nj*16+l16
    #pragma unroll
    for (int cj = 0; cj < 4; ++cj)
        #pragma unroll
        for (int nj = 0; nj < 2; ++nj) pv[cj][nj] = (f32x4){0.f, 0.f, 0.f, 0.f};
    float runm = -3.0e38f, zacc = 0.f;

    stage(0, mbase);

    #pragma unroll
    for (int tt = 0; tt < MT; ++tt) {
        const _Float16* lt = ltop[tt & 1];
        const _Float16* lb = lbot[tt & 1];
        __syncthreads();   // drains this wave's gloads; prev compute done block-wide
        if (tt + 1 < MT) stage((tt + 1) & 1, mbase + (tt + 1) * 64);
        // S^T = top * cen^T: sa[mi][nj], row m = mi*16+quad*4+r, col n = nj*16+l16
        f32x4 sa[4][2];
        #pragma unroll
        for (int mi = 0; mi < 4; ++mi)
            #pragma unroll
            for (int nj = 0; nj < 2; ++nj) sa[mi][nj] = (f32x4){0.f, 0.f, 0.f, 0.f};
        __builtin_amdgcn_s_setprio(1);
        #pragma unroll
        for (int kk = 0; kk < 2; ++kk)
            #pragma unroll
            for (int mi = 0; mi < 4; ++mi) {
                half8v at = *(half8v*)&lt[(mi * 16 + l16) * 64 + ((kk * 32 + quad * 8) ^ rsw)];
                sa[mi][0] = __builtin_amdgcn_mfma_f32_16x16x32_f16(at, bcen[0][kk], sa[mi][0], 0, 0, 0);
                sa[mi][1] = __builtin_amdgcn_mfma_f32_16x16x32_f16(at, bcen[1][kk], sa[mi][1], 0, 0, 0);
            }
        __builtin_amdgcn_s_setprio(0);
        // lane-local tile max
        float lm = -3.0e38f;
        #pragma unroll
        for (int mi = 0; mi < 4; ++mi)
            #pragma unroll
            for (int nj = 0; nj < 2; ++nj) {
                float a  = fmaxf(sa[mi][nj][0], sa[mi][nj][1]);
                float c2 = fmaxf(sa[mi][nj][2], sa[mi][nj][3]);
                lm = fmaxf(lm, fmaxf(a, c2));
            }
        // T13 defer-max: only reduce+rescale when some lane exceeds runm+8
        if (!__all(lm - runm <= 8.0f)) {
            float tm = lm;
            for (int o2 = 32; o2; o2 >>= 1) tm = fmaxf(tm, __shfl_xor(tm, o2, 64));
            if (tm > runm) {
                float sc = __builtin_amdgcn_exp2f(runm - tm);
                zacc *= sc;
                #pragma unroll
                for (int cj = 0; cj < 4; ++cj)
                    #pragma unroll
                    for (int nj = 0; nj < 2; ++nj) pv[cj][nj] *= sc;
                runm = tm;
            }
        }
        // Per kb (32-m half): exp2 -> fp16 pack -> pure-VALU quad exchange -> PV
        #pragma unroll
        for (int kb = 0; kb < 2; ++kb) {
            unsigned pk[2][2][2];   // [f = mi&1][nj][d]
            #pragma unroll
            for (int f = 0; f < 2; ++f) {
                int mi = 2 * kb + f;
                #pragma unroll
                for (int nj = 0; nj < 2; ++nj) {
                    float e0 = __builtin_amdgcn_exp2f(sa[mi][nj][0] - runm);
                    float e1 = __builtin_amdgcn_exp2f(sa[mi][nj][1] - runm);
                    float e2 = __builtin_amdgcn_exp2f(sa[mi][nj][2] - runm);
                    float e3 = __builtin_amdgcn_exp2f(sa[mi][nj][3] - runm);
                    zacc += (e0 + e1) + (e2 + e3);
                    pk[f][nj][0] = pkrtz(e0, e1);
                    pk[f][nj][1] = pkrtz(e2, e3);
                }
            }
            // Exchange: dst lane(quad q) holds m = kb*32 + q*8 + 0..7 for its n-col.
            // p32swap: X=[Xq0,Xq1,Yq0,Yq1], Y=[Xq2,Xq3,Yq2,Yq3];
            // p16swap: X=[Xq0,Xq2,Yq0,Yq2]=T[d], Y=[Xq1,Xq3,Yq1,Yq3]=T[d+2].
            half8v pa[2];
            #pragma unroll
            for (int nj = 0; nj < 2; ++nj) {
                unsigned T[4];
                #pragma unroll
                for (int d = 0; d < 2; ++d) {
                    unsigned X = pk[0][nj][d], Y = pk[1][nj][d];
                    asm("v_permlane32_swap_b32 %0, %1" : "+v"(X), "+v"(Y));
                    asm("v_permlane16_swap_b32 %0, %1" : "+v"(X), "+v"(Y));
                    T[d]     = X;
                    T[d + 2] = Y;
                }
                uint4v tv = {T[0], T[1], T[2], T[3]};
                pa[nj] = __builtin_bit_cast(half8v, tv);
            }
            __builtin_amdgcn_s_setprio(1);
            #pragma unroll
            for (int cj = 0; cj < 4; ++cj) {
                half8v ab = *(half8v*)&lb[(cj * 16 + l16) * 64 + ((kb * 32 + quad * 8) ^ rsw)];
                pv[cj][0] = __builtin_amdgcn_mfma_f32_16x16x32_f16(ab, pa[0], pv[cj][0], 0, 0, 0);
                pv[cj][1] = __builtin_amdgcn_mfma_f32_16x16x32_f16(ab, pa[1], pv[cj][1], 0, 0, 0);
            }
            __builtin_amdgcn_s_setprio(0);
        }
    }
    for (int o2 = 32; o2; o2 >>= 1) zacc += __shfl_xor(zacc, o2, 64);
    if (lane == 0) {
        ws[msoOff + s * 512 + b * 128 + st * 4 + w] = runm;
        ws[zsoOff + s * 512 + b * 128 + st * 4 + w] = zacc;
    }
    // O^T frags -> PV[n][c] bf16, coalesced 8B stores (4 consecutive c per lane)
    short* pvp = (short*)(ws + PVO) + (size_t)s * 1048576 + (size_t)b * IMG;
    #pragma unroll
    for (int cj = 0; cj < 4; ++cj)
        #pragma unroll
        for (int nj = 0; nj < 2; ++nj) {
            short4v o;
            #pragma unroll
            for (int r = 0; r < 4; ++r) o[r] = f2bf(pv[cj][nj][r]);
            *(short4v*)&pvp[(size_t)(n0 + w * 32 + nj * 16 + l16) * 64 + cj * 16 + quad * 4] = o;
        }
}

// ---- Dispatch 4: inline M/Z reduction + u = x + softmax@bottom (short8 PV reads)
// + u-powers -> quad-plane padded fp16. 512 threads/block.
__global__ __launch_bounds__(512) void k_finalu(const float* __restrict__ x, float* __restrict__ ws,
                                                _Float16* __restrict__ upad,
                                                int ms, int msoOff, int zsoOff) {
    __shared__ float us[64 * 65];
    __shared__ float rm[8], rz[8];
    int t = threadIdx.x, bx = blockIdx.x;
    int b = bx >> 6, h = bx & 63;
    int g = t & 127;   // group index (duplicated across t>=128; z guarded)
    float m = -3.0e38f;
    for (int s = 0; s < ms; ++s)
        m = fmaxf(m, ws[msoOff + s * 512 + b * 128 + g]);
    for (int o2 = 32; o2; o2 >>= 1) m = fmaxf(m, __shfl_xor(m, o2, 64));
    if ((t & 63) == 0) rm[t >> 6] = m;
    __syncthreads();
    float M = rm[0];
    #pragma unroll
    for (int j = 1; j < 8; ++j) M = fmaxf(M, rm[j]);
    float z = 0.f;
    if (t < 128) {
        for (int s = 0; s < ms; ++s)
            z += ws[zsoOff + s * 512 + b * 128 + g] *
                 __builtin_amdgcn_exp2f(ws[msoOff + s * 512 + b * 128 + g] - M);
    }
    for (int o2 = 32; o2; o2 >>= 1) z += __shfl_xor(z, o2, 64);
    if ((t & 63) == 0) rz[t >> 6] = z;
    __syncthreads();
    float Z = 0.f;
    #pragma unroll
    for (int j = 0; j < 8; ++j) Z += rz[j];
    float rZ = 1.0f / Z;

    const short* pvb = (const short*)(ws + PVO) + (size_t)b * IMG;
    int hg = h >> 5;
    {
        int idx = t * 8;                  // 512 threads x 8 = 4096 elems exact
        int ci = idx >> 6, wc = idx & 63;
        int rem = ci * 4096 + h * 64 + wc;
        int grp = ci * 2 + hg;            // n = ci*64+h; 32-row group = n>>5
        float acc[8] = {};
        for (int s = 0; s < ms; ++s) {
            float scl = __builtin_amdgcn_exp2f(ws[msoOff + s * 512 + b * 128 + grp] - M);
            short8v pvv = *(const short8v*)&pvb[(size_t)s * 1048576 + rem];
            #pragma unroll
            for (int i = 0; i < 8; ++i) acc[i] += bf2f(pvv[i]) * scl;
        }
        float4 x0 = *(const float4*)&x[(size_t)b * IMG + rem];
        float4 x1 = *(const float4*)&x[(size_t)b * IMG + rem + 4];
        float xv[8] = {x0.x, x0.y, x0.z, x0.w, x1.x, x1.y, x1.z, x1.w};
        #pragma unroll
        for (int i = 0; i < 8; ++i)
            us[ci * 65 + wc + i] = xv[i] + acc[i] * rZ;
    }
    __syncthreads();
    _Float16* dst = upad + ((size_t)b * 24 * PADIMG + (h + 1) * 66 + 1) * 8;
    #pragma unroll
    for (int it = 0; it < 3; ++it) {
        int u = it * 512 + t;             // 1536 units
        int ck = u >> 8, within = u & 255;
        int q = within >> 6, px = within & 63;   // px fastest -> contiguous stores
        int k0 = ck * 32 + q * 8;
        int p = k0 >> 6, c0 = k0 & 63;
        half8v o;
        #pragma unroll
        for (int j = 0; j < 8; ++j) {
            float v = us[(c0 + j) * 65 + px];
            float pw = (p == 0) ? v : ((p == 1) ? v * v : v * v * v);
            o[j] = (_Float16)pw;
        }
        *(half8v*)&dst[((size_t)(ck * 4 + q) * PADIMG + px) * 8] = o;
    }
}

// ---- Dispatch 5: final 3x3 conv, direct fp32 output + bias, oc-32. grid 512.
__global__ __launch_bounds__(256) void k_conv3o(const _Float16* __restrict__ upad,
                                                const _Float16* __restrict__ wout,
                                                const float* __restrict__ ob,
                                                float* __restrict__ out) {
    conv3d32(blockIdx.x, threadIdx.x, upad, wout, ob, nullptr, out);
}

extern "C" void kernel_launch(void* const* d_in, const int* in_sizes, int n_in,
                              void* d_out, int out_size, void* d_ws, size_t ws_size,
                              hipStream_t stream) {
    (void)in_sizes; (void)n_in; (void)out_size;
    const float* x  = (const float*)d_in[0];
    const float* tw = (const float*)d_in[1];
    const float* tb = (const float*)d_in[2];
    const float* cw = (const float*)d_in[3];
    const float* cb = (const float*)d_in[4];
    const float* bw = (const float*)d_in[5];
    const float* bb = (const float*)d_in[6];
    const float* ow = (const float*)d_in[7];
    const float* ob = (const float*)d_in[8];
    float* ws  = (float*)d_ws;
    float* out = (float*)d_out;

    _Float16* wbf  = (_Float16*)(ws + WBFO);
    _Float16* wout = wbf + 110592;
    _Float16* xpad = (_Float16*)(ws + XPADO);   // also upad (aliased)
    _Float16* topb = (_Float16*)(ws + TOPO);
    _Float16* cenb = (_Float16*)(ws + CENO);
    _Float16* botb = (_Float16*)(ws + BOTO);

    // m-split count: 8 (grid 1024) when the workspace can hold the 16MB PV
    // buffer; otherwise fall back to the proven 4-split layout.
    int ms     = (ws_size >= NEED8) ? 8 : 4;
    int msoOff = (ms == 8) ? MSO8 : MSO4;
    int zsoOff = msoOff + ms * 512;

    hipLaunchKernelGGL(k_prep, dim3(1216), dim3(256), 0, stream, bw, ow, tw, cw, wbf, x, xpad);
    hipLaunchKernelGGL(k_convs, dim3(1024), dim3(256), 0, stream, xpad, wbf, tb, cb, bb, topb, cenb, botb);
    if (ms == 8)
        hipLaunchKernelGGL(k_attn<8>,  dim3(1024), dim3(256), 0, stream, ws, msoOff, zsoOff);
    else
        hipLaunchKernelGGL(k_attn<16>, dim3(512),  dim3(256), 0, stream, ws, msoOff, zsoOff);
    hipLaunchKernelGGL(k_finalu, dim3(256), dim3(512), 0, stream, x, ws, xpad, ms, msoOff, zsoOff);
    hipLaunchKernelGGL(k_conv3o, dim3(512), dim3(256), 0, stream, xpad, wout, ob, out);
}

// Round 13
// 141.278 us; speedup vs baseline: 1.1293x; 1.0101x over previous
//
#include <hip/hip_runtime.h>
#include <hip/hip_bf16.h>

// Problem constants: B=4, C=64, H=W=64, HW=4096, P=64, Q=3 (CQ=192)
namespace {
constexpr int IMG    = 262144;   // 64*4096 elems per batch image
constexpr int PADIMG = 4356;     // 66*66 padded pixels
constexpr float LOG2E = 1.44269504088896340736f;
// workspace float offsets
constexpr int WBFO  = 0;         // fp16 weights, quad-plane: w[tap][ck][q][o][8]
constexpr int XPADO = 122880;    // fp16 xp/up padded [b][ck 6][quad 4][px 4356][8] (aliased: xp then up)
constexpr int TOPO  = 1795584;   // fp16 topT [b][m][p]
constexpr int CENO  = 2319872;   // fp16 cenT [b][n][p]
constexpr int BOTO  = 2844160;   // fp16 bot  [b][c][m]
constexpr int PVO   = 3368448;   // bf16 PV [ms][b][n][c]
// M/Z scratch [s][b 4][group 128]: placement depends on m-split count (PV size)
constexpr int MSO4  = 5465600;   // ms=4 legacy layout (PV = 8MB)
constexpr int MSO8  = 7562752;   // ms=8 layout (PV = 16MB)
constexpr size_t NEED8 = (size_t)(MSO8 + 8192) * 4;   // ~30.3 MB workspace for ms=8
}

using half8v  = __attribute__((ext_vector_type(8))) _Float16;
using half4v  = __attribute__((ext_vector_type(4))) _Float16;
using short8v = __attribute__((ext_vector_type(8))) short;
using short4v = __attribute__((ext_vector_type(4))) short;
using uint4v  = __attribute__((ext_vector_type(4))) unsigned;
typedef __attribute__((ext_vector_type(4))) float f32x4;

__device__ __forceinline__ short f2bf(float f) {
    __hip_bfloat16 h = __float2bfloat16(f);
    return *reinterpret_cast<short*>(&h);
}
__device__ __forceinline__ float bf2f(short s) {
    unsigned u = ((unsigned)(unsigned short)s) << 16;
    return __uint_as_float(u);
}
__device__ __forceinline__ unsigned pkrtz(float a, float b) {
    return __builtin_bit_cast(unsigned, __builtin_amdgcn_cvt_pkrtz(a, b));
}
// async global->LDS, 16B/lane. LDS dest is wave-uniform base + lane*16 (m104);
// pass the uniform base, per-lane global src.
__device__ __forceinline__ void gload16(const void* g, void* l) {
    __builtin_amdgcn_global_load_lds(
        (const __attribute__((address_space(1))) unsigned*)g,
        (__attribute__((address_space(3))) unsigned*)l, 16, 0, 0);
}

// ---- Dispatch 1: weights->fp16 reorder into QUAD-PLANE k-chunked layouts
// (blocks 0..959) + x-powers into quad-plane padded xpad incl. border zeroing
// (blocks 960..1215).
__global__ __launch_bounds__(256) void k_prep(const float* __restrict__ bw, const float* __restrict__ ow,
                                              const float* __restrict__ tw, const float* __restrict__ cw,
                                              _Float16* __restrict__ wbf,
                                              const float* __restrict__ x, _Float16* __restrict__ xpad) {
    __shared__ float xs[64 * 65];
    int bx = blockIdx.x, t = threadIdx.x;
    if (bx < 960) {
        int idx = bx * 256 + t;   // < 245760
        if (idx < 221184) {
            // 3x3: w[o][(p*64+ci)*9+tap] -> wT[tap][ck][q][o][j]
            int tsel = idx / 110592;
            int r    = idx - tsel * 110592;
            int tap  = r / 12288;
            int rr   = r - tap * 12288;
            int ck   = rr / 2048;
            int r2   = rr - ck * 2048;
            int q    = r2 >> 9;
            int o    = (r2 >> 3) & 63;
            int j    = r2 & 7;
            int k    = ck * 32 + q * 8 + j;
            int p    = k >> 6, ci = k & 63;
            const float* src = tsel ? ow : bw;
            wbf[idx] = (_Float16)src[o * 1728 + (p * 64 + ci) * 9 + tap];
        } else {
            // 1x1: w[o][192] -> wT[ck][q][o][j]; center pre-scaled by log2(e)
            int jx = idx - 221184;
            int tsel = jx / 12288;
            int rr   = jx - tsel * 12288;
            int ck   = rr / 2048;
            int r2   = rr - ck * 2048;
            int q    = r2 >> 9;
            int o    = (r2 >> 3) & 63;
            int j    = r2 & 7;
            int k    = ck * 32 + q * 8 + j;
            wbf[idx] = (_Float16)(tsel ? cw[o * 192 + k] * LOG2E : tw[o * 192 + k]);
        }
        return;
    }
    int bx2 = bx - 960;
    int b = bx2 >> 6, h = bx2 & 63;
    // zero this block's share of the pad border across all 24 quad-planes
    {
        _Float16* base = xpad + (size_t)b * 24 * PADIMG * 8;
        int px[6];
        px[0] = (h + 1) * 66;
        px[1] = (h + 1) * 66 + 65;
        px[2] = h;
        px[3] = 65 * 66 + h;
        int npx = 4;
        if (h < 2) { px[4] = 64 + h; px[5] = 65 * 66 + 64 + h; npx = 6; }
        int pi = t / 24, cpq = t % 24;
        if (pi < npx) {
            half8v z = {0, 0, 0, 0, 0, 0, 0, 0};
            *(half8v*)&base[((size_t)cpq * PADIMG + px[pi]) * 8] = z;
        }
    }
    #pragma unroll
    for (int it = 0; it < 16; ++it) {
        int idx = it * 256 + t;
        int ci = idx >> 6, wc = idx & 63;
        xs[ci * 65 + wc] = x[b * IMG + ci * 4096 + h * 64 + wc];
    }
    __syncthreads();
    _Float16* dst = xpad + ((size_t)b * 24 * PADIMG + (h + 1) * 66 + 1) * 8;
    #pragma unroll
    for (int it = 0; it < 6; ++it) {
        int u = it * 256 + t;
        int ck = u >> 8, within = u & 255;
        int q = within >> 6, px = within & 63;   // px fastest -> contiguous stores
        int k0 = ck * 32 + q * 8;
        int p = k0 >> 6, c0 = k0 & 63;
        half8v o;
        #pragma unroll
        for (int j = 0; j < 8; ++j) {
            float v = xs[(c0 + j) * 65 + px];
            float pw = (p == 0) ? v : ((p == 1) ? v * v : v * v * v);
            o[j] = (_Float16)pw;
        }
        *(half8v*)&dst[((size_t)(ck * 4 + q) * PADIMG + px) * 8] = o;
    }
}

// 3x3 SelfONN conv, full-K MFMA implicit GEMM, 32 oc/block.
// R13: LDS-transpose epilogue -> coalesced output stores (8x256B fp32 or
// 8x128B fp16 per instruction, was 16 scattered 32-64B segments).
__device__ __forceinline__ void conv3d32(int bx, int t, float* __restrict__ ts /*[32*68] LDS*/,
                                         const _Float16* __restrict__ src,
                                         const _Float16* __restrict__ wt,
                                         const float* __restrict__ bias,
                                         _Float16* __restrict__ dh_, float* __restrict__ df) {
    int lane = t & 63, w = t >> 6;
    int l16 = lane & 15, quad = lane >> 4;
    int oh = bx >> 8, mt = bx & 255;
    int b = mt >> 6, h = mt & 63;
    const _Float16* abase = src + ((size_t)(b * 24 + quad) * PADIMG + (h + 1) * 66 + 1 + w * 16 + l16) * 8;
    const _Float16* bbase = wt + (size_t)(oh * 32 + l16) * 8 + quad * 512;
    f32x4 acc[2];
    acc[0] = (f32x4){0.f, 0.f, 0.f, 0.f};
    acc[1] = (f32x4){0.f, 0.f, 0.f, 0.f};
    #pragma unroll
    for (int tap = 0; tap < 9; ++tap) {
        int dh = tap / 3 - 1, dw = tap % 3 - 1;
        const _Float16* arow = abase + (dh * 66 + dw) * 8;
        const _Float16* brow = bbase + (size_t)tap * 12288;
        #pragma unroll
        for (int c6 = 0; c6 < 6; ++c6) {
            half8v afr  = *(const half8v*)&arow[(size_t)c6 * 4 * PADIMG * 8];
            half8v bfr0 = *(const half8v*)&brow[(size_t)c6 * 2048];
            half8v bfr1 = *(const half8v*)&brow[(size_t)c6 * 2048 + 128];
            acc[0] = __builtin_amdgcn_mfma_f32_16x16x32_f16(afr, bfr0, acc[0], 0, 0, 0);
            acc[1] = __builtin_amdgcn_mfma_f32_16x16x32_f16(afr, bfr1, acc[1], 0, 0, 0);
        }
    }
    // epilogue: stage [c-local 32][hw-local 64] (pad 68, 16B-aligned rows)
    int col = w * 16 + quad * 4;
    #pragma unroll
    for (int nf = 0; nf < 2; ++nf) {
        float bv = bias[oh * 32 + nf * 16 + l16];
        f32x4 v = acc[nf];
        v[0] += bv; v[1] += bv; v[2] += bv; v[3] += bv;
        *(f32x4*)&ts[(nf * 16 + l16) * 68 + col] = v;
    }
    __syncthreads();
    int cl = t >> 3, hw0 = (t & 7) * 8;
    float4 v0 = *(float4*)&ts[cl * 68 + hw0];
    float4 v1 = *(float4*)&ts[cl * 68 + hw0 + 4];
    size_t oi = (size_t)b * 262144 + (size_t)(oh * 32 + cl) * 4096 + h * 64 + hw0;
    if (dh_) {
        half8v o;
        o[0] = (_Float16)v0.x; o[1] = (_Float16)v0.y; o[2] = (_Float16)v0.z; o[3] = (_Float16)v0.w;
        o[4] = (_Float16)v1.x; o[5] = (_Float16)v1.y; o[6] = (_Float16)v1.z; o[7] = (_Float16)v1.w;
        *(half8v*)&dh_[oi] = o;
    } else {
        *(float4*)&df[oi] = v0;
        *(float4*)&df[oi + 4] = v1;
    }
}

// ---- Dispatch 2: conv3-bottom (blocks 0..511, fp16 out, oc-32) + fused
// top/center 1x1 convs (blocks 512..1023). Both paths use LDS-transpose stores.
__global__ __launch_bounds__(256) void k_convs(const _Float16* __restrict__ xpad,
                                               const _Float16* __restrict__ wbf,
                                               const float* __restrict__ tb, const float* __restrict__ cb,
                                               const float* __restrict__ bbias,
                                               _Float16* __restrict__ topd, _Float16* __restrict__ cend,
                                               _Float16* __restrict__ botb) {
    __shared__ __align__(16) char smem[64 * 72 * 2];   // >= 32*68*4 too
    int bx = blockIdx.x, t = threadIdx.x;
    if (bx < 512) {
        conv3d32(bx, t, (float*)smem, xpad, wbf /* wbot at offset 0 */, bbias, botb, nullptr);
        return;
    }
    int bx2 = bx - 512;
    int lane = t & 63, w = t >> 6;
    int l16 = lane & 15, quad = lane >> 4;
    int ot = bx2 >> 8, mt = bx2 & 255;
    int b = mt >> 6, h = mt & 63;
    const _Float16* wt   = wbf + (ot ? 233472 : 221184);   // wcen : wtop
    const float*    bias = ot ? cb : tb;
    _Float16*       dst  = (ot ? cend : topd) + (size_t)b * IMG;
    const _Float16* abase = xpad + ((size_t)(b * 24 + quad) * PADIMG + (h + 1) * 66 + 1 + w * 16 + l16) * 8;
    const _Float16* bbase = wt + (size_t)l16 * 8 + quad * 512;
    f32x4 acc[4];
    #pragma unroll
    for (int nf = 0; nf < 4; ++nf) acc[nf] = (f32x4){0.f, 0.f, 0.f, 0.f};
    #pragma unroll
    for (int kc = 0; kc < 6; ++kc) {
        half8v afr = *(const half8v*)&abase[(size_t)kc * 4 * PADIMG * 8];
        #pragma unroll
        for (int nf = 0; nf < 4; ++nf) {
            half8v bfr = *(const half8v*)&bbase[(size_t)kc * 2048 + nf * 128];
            acc[nf] = __builtin_amdgcn_mfma_f32_16x16x32_f16(afr, bfr, acc[nf], 0, 0, 0);
        }
    }
    // epilogue: stage [hw-local 64][c 64] (pad 72), then 2x b128 rows out
    _Float16* ts2 = (_Float16*)smem;
    #pragma unroll
    for (int nf = 0; nf < 4; ++nf) {
        float bv = bias[nf * 16 + l16];
        if (ot) bv *= LOG2E;   // center output lives in log2e-scaled domain
        #pragma unroll
        for (int r = 0; r < 4; ++r)
            ts2[(w * 16 + quad * 4 + r) * 72 + nf * 16 + l16] = (_Float16)(acc[nf][r] + bv);
    }
    __syncthreads();
    int hwl = t >> 2, c0 = (t & 3) * 16;
    half8v u0 = *(half8v*)&ts2[hwl * 72 + c0];
    half8v u1 = *(half8v*)&ts2[hwl * 72 + c0 + 8];
    _Float16* dq = dst + (size_t)(h * 64 + hwl) * 64 + c0;
    *(half8v*)&dq[0] = u0;
    *(half8v*)&dq[8] = u1;
}

// ---- Dispatch 3: fp16 MFMA flash attention, global softmax (unchanged from R10:
// launch_bounds(256,4), gload_lds staging with pre-swizzled source, XOR-swizzled
// unpadded LDS, in-reg P via permlane32+16 exchange, defer-max, 1 barrier/tile).
template<int MT>
__global__ __launch_bounds__(256, 4) void k_attn(float* __restrict__ ws, int msoOff, int zsoOff) {
    __shared__ _Float16 ltop[2][64 * 64];    // [buf][m][p swizzled]
    __shared__ _Float16 lbot[2][64 * 64];    // [buf][c][m swizzled]
    int t    = threadIdx.x;
    int lane = t & 63, w = t >> 6;
    int l16  = lane & 15, quad = lane >> 4;
    int bxr = blockIdx.x;
    int bx  = (bxr & 7) * ((int)gridDim.x >> 3) + (bxr >> 3);
    int st = bx & 31, b = (bx >> 5) & 3, s = bx >> 7;
    int n0 = st * 128;
    int mbase = s * MT * 64;
    const _Float16* topg = (const _Float16*)(ws + TOPO) + (size_t)b * IMG;
    const _Float16* ceng = (const _Float16*)(ws + CENO) + (size_t)b * IMG;
    const _Float16* botg = (const _Float16*)(ws + BOTO) + (size_t)b * IMG;

    int r0   = t >> 3;                       // 0..31 (and +32 for 2nd half)
    int swz0 = ((t & 7) ^ (r0 & 7)) * 8;     // halves
    int rsw  = (l16 & 7) * 8;                // read-side XOR (halves)

    auto stage = [&](int buf, int mt) {
        gload16(topg + (size_t)(mt + r0) * 64 + swz0,      &ltop[buf][w * 512]);
        gload16(topg + (size_t)(mt + r0 + 32) * 64 + swz0, &ltop[buf][2048 + w * 512]);
        gload16(botg + (size_t)r0 * 4096 + mt + swz0,      &lbot[buf][w * 512]);
        gload16(botg + (size_t)(r0 + 32) * 4096 + mt + swz0, &lbot[buf][2048 + w * 512]);
    };

    // B-frag of QK^T: cen, register-resident. lane l16 = n-col, quad*8 = k(p)
    half8v bcen[2][2];   // [nj][kk]
    #pragma unroll
    for (int nj = 0; nj < 2; ++nj)
        #pragma unroll
        for (int kk = 0; kk < 2; ++kk)
            bcen[nj][kk] = *(const half8v*)&ceng[(size_t)(n0 + w * 32 + nj * 16 + l16) * 64 + kk * 32 + quad * 8];

    f32x4 pv[4][2];   // O^T frags: [cj][nj], row c = cj*16+quad*4+r, col n = nj*16+l16
    #pragma unroll
    for (int cj = 0; cj < 4; ++cj)
        #pragma unroll
        for (int nj = 0; nj < 2; ++nj) pv[cj][nj] = (f32x4){0.f, 0.f, 0.f, 0.f};
    float runm = -3.0e38f, zacc = 0.f;

    stage(0, mbase);

    #pragma unroll
    for (int tt = 0; tt < MT; ++tt) {
        const _Float16* lt = ltop[tt & 1];
        const _Float16* lb = lbot[tt & 1];
        __syncthreads();   // drains this wave's gloads; prev compute done block-wide
        if (tt + 1 < MT) stage((tt + 1) & 1, mbase + (tt + 1) * 64);
        // S^T = top * cen^T: sa[mi][nj], row m = mi*16+quad*4+r, col n = nj*16+l16
        f32x4 sa[4][2];
        #pragma unroll
        for (int mi = 0; mi < 4; ++mi)
            #pragma unroll
            for (int nj = 0; nj < 2; ++nj) sa[mi][nj] = (f32x4){0.f, 0.f, 0.f, 0.f};
        __builtin_amdgcn_s_setprio(1);
        #pragma unroll
        for (int kk = 0; kk < 2; ++kk)
            #pragma unroll
            for (int mi = 0; mi < 4; ++mi) {
                half8v at = *(half8v*)&lt[(mi * 16 + l16) * 64 + ((kk * 32 + quad * 8) ^ rsw)];
                sa[mi][0] = __builtin_amdgcn_mfma_f32_16x16x32_f16(at, bcen[0][kk], sa[mi][0], 0, 0, 0);
                sa[mi][1] = __builtin_amdgcn_mfma_f32_16x16x32_f16(at, bcen[1][kk], sa[mi][1], 0, 0, 0);
            }
        __builtin_amdgcn_s_setprio(0);
        // lane-local tile max
        float lm = -3.0e38f;
        #pragma unroll
        for (int mi = 0; mi < 4; ++mi)
            #pragma unroll
            for (int nj = 0; nj < 2; ++nj) {
                float a  = fmaxf(sa[mi][nj][0], sa[mi][nj][1]);
                float c2 = fmaxf(sa[mi][nj][2], sa[mi][nj][3]);
                lm = fmaxf(lm, fmaxf(a, c2));
            }
        // T13 defer-max: only reduce+rescale when some lane exceeds runm+8
        if (!__all(lm - runm <= 8.0f)) {
            float tm = lm;
            for (int o2 = 32; o2; o2 >>= 1) tm = fmaxf(tm, __shfl_xor(tm, o2, 64));
            if (tm > runm) {
                float sc = __builtin_amdgcn_exp2f(runm - tm);
                zacc *= sc;
                #pragma unroll
                for (int cj = 0; cj < 4; ++cj)
                    #pragma unroll
                    for (int nj = 0; nj < 2; ++nj) pv[cj][nj] *= sc;
                runm = tm;
            }
        }
        // Per kb (32-m half): exp2 -> fp16 pack -> pure-VALU quad exchange -> PV
        #pragma unroll
        for (int kb = 0; kb < 2; ++kb) {
            unsigned pk[2][2][2];   // [f = mi&1][nj][d]
            #pragma unroll
            for (int f = 0; f < 2; ++f) {
                int mi = 2 * kb + f;
                #pragma unroll
                for (int nj = 0; nj < 2; ++nj) {
                    float e0 = __builtin_amdgcn_exp2f(sa[mi][nj][0] - runm);
                    float e1 = __builtin_amdgcn_exp2f(sa[mi][nj][1] - runm);
                    float e2 = __builtin_amdgcn_exp2f(sa[mi][nj][2] - runm);
                    float e3 = __builtin_amdgcn_exp2f(sa[mi][nj][3] - runm);
                    zacc += (e0 + e1) + (e2 + e3);
                    pk[f][nj][0] = pkrtz(e0, e1);
                    pk[f][nj][1] = pkrtz(e2, e3);
                }
            }
            // Exchange: dst lane(quad q) holds m = kb*32 + q*8 + 0..7 for its n-col.
            // p32swap: X=[Xq0,Xq1,Yq0,Yq1], Y=[Xq2,Xq3,Yq2,Yq3];
            // p16swap: X=[Xq0,Xq2,Yq0,Yq2]=T[d], Y=[Xq1,Xq3,Yq1,Yq3]=T[d+2].
            half8v pa[2];
            #pragma unroll
            for (int nj = 0; nj < 2; ++nj) {
                unsigned T[4];
                #pragma unroll
                for (int d = 0; d < 2; ++d) {
                    unsigned X = pk[0][nj][d], Y = pk[1][nj][d];
                    asm("v_permlane32_swap_b32 %0, %1" : "+v"(X), "+v"(Y));
                    asm("v_permlane16_swap_b32 %0, %1" : "+v"(X), "+v"(Y));
                    T[d]     = X;
                    T[d + 2] = Y;
                }
                uint4v tv = {T[0], T[1], T[2], T[3]};
                pa[nj] = __builtin_bit_cast(half8v, tv);
            }
            __builtin_amdgcn_s_setprio(1);
            #pragma unroll
            for (int cj = 0; cj < 4; ++cj) {
                half8v ab = *(half8v*)&lb[(cj * 16 + l16) * 64 + ((kb * 32 + quad * 8) ^ rsw)];
                pv[cj][0] = __builtin_amdgcn_mfma_f32_16x16x32_f16(ab, pa[0], pv[cj][0], 0, 0, 0);
                pv[cj][1] = __builtin_amdgcn_mfma_f32_16x16x32_f16(ab, pa[1], pv[cj][1], 0, 0, 0);
            }
            __builtin_amdgcn_s_setprio(0);
        }
    }
    for (int o2 = 32; o2; o2 >>= 1) zacc += __shfl_xor(zacc, o2, 64);
    if (lane == 0) {
        ws[msoOff + s * 512 + b * 128 + st * 4 + w] = runm;
        ws[zsoOff + s * 512 + b * 128 + st * 4 + w] = zacc;
    }
    // O^T frags -> PV[n][c] bf16, coalesced 8B stores (4 consecutive c per lane)
    short* pvp = (short*)(ws + PVO) + (size_t)s * 1048576 + (size_t)b * IMG;
    #pragma unroll
    for (int cj = 0; cj < 4; ++cj)
        #pragma unroll
        for (int nj = 0; nj < 2; ++nj) {
            short4v o;
            #pragma unroll
            for (int r = 0; r < 4; ++r) o[r] = f2bf(pv[cj][nj][r]);
            *(short4v*)&pvp[(size_t)(n0 + w * 32 + nj * 16 + l16) * 64 + cj * 16 + quad * 4] = o;
        }
}

// ---- Dispatch 4: inline M/Z reduction + u = x + softmax@bottom (short8 PV reads)
// + u-powers -> quad-plane padded fp16. 512 threads/block.
__global__ __launch_bounds__(512) void k_finalu(const float* __restrict__ x, float* __restrict__ ws,
                                                _Float16* __restrict__ upad,
                                                int ms, int msoOff, int zsoOff) {
    __shared__ float us[64 * 65];
    __shared__ float rm[8], rz[8];
    int t = threadIdx.x, bx = blockIdx.x;
    int b = bx >> 6, h = bx & 63;
    int g = t & 127;   // group index (duplicated across t>=128; z guarded)
    float m = -3.0e38f;
    for (int s = 0; s < ms; ++s)
        m = fmaxf(m, ws[msoOff + s * 512 + b * 128 + g]);
    for (int o2 = 32; o2; o2 >>= 1) m = fmaxf(m, __shfl_xor(m, o2, 64));
    if ((t & 63) == 0) rm[t >> 6] = m;
    __syncthreads();
    float M = rm[0];
    #pragma unroll
    for (int j = 1; j < 8; ++j) M = fmaxf(M, rm[j]);
    float z = 0.f;
    if (t < 128) {
        for (int s = 0; s < ms; ++s)
            z += ws[zsoOff + s * 512 + b * 128 + g] *
                 __builtin_amdgcn_exp2f(ws[msoOff + s * 512 + b * 128 + g] - M);
    }
    for (int o2 = 32; o2; o2 >>= 1) z += __shfl_xor(z, o2, 64);
    if ((t & 63) == 0) rz[t >> 6] = z;
    __syncthreads();
    float Z = 0.f;
    #pragma unroll
    for (int j = 0; j < 8; ++j) Z += rz[j];
    float rZ = 1.0f / Z;

    const short* pvb = (const short*)(ws + PVO) + (size_t)b * IMG;
    int hg = h >> 5;
    {
        int idx = t * 8;                  // 512 threads x 8 = 4096 elems exact
        int ci = idx >> 6, wc = idx & 63;
        int rem = ci * 4096 + h * 64 + wc;
        int grp = ci * 2 + hg;            // n = ci*64+h; 32-row group = n>>5
        float acc[8] = {};
        for (int s = 0; s < ms; ++s) {
            float scl = __builtin_amdgcn_exp2f(ws[msoOff + s * 512 + b * 128 + grp] - M);
            short8v pvv = *(const short8v*)&pvb[(size_t)s * 1048576 + rem];
            #pragma unroll
            for (int i = 0; i < 8; ++i) acc[i] += bf2f(pvv[i]) * scl;
        }
        float4 x0 = *(const float4*)&x[(size_t)b * IMG + rem];
        float4 x1 = *(const float4*)&x[(size_t)b * IMG + rem + 4];
        float xv[8] = {x0.x, x0.y, x0.z, x0.w, x1.x, x1.y, x1.z, x1.w};
        #pragma unroll
        for (int i = 0; i < 8; ++i)
            us[ci * 65 + wc + i] = xv[i] + acc[i] * rZ;
    }
    __syncthreads();
    _Float16* dst = upad + ((size_t)b * 24 * PADIMG + (h + 1) * 66 + 1) * 8;
    #pragma unroll
    for (int it = 0; it < 3; ++it) {
        int u = it * 512 + t;             // 1536 units
        int ck = u >> 8, within = u & 255;
        int q = within >> 6, px = within & 63;   // px fastest -> contiguous stores
        int k0 = ck * 32 + q * 8;
        int p = k0 >> 6, c0 = k0 & 63;
        half8v o;
        #pragma unroll
        for (int j = 0; j < 8; ++j) {
            float v = us[(c0 + j) * 65 + px];
            float pw = (p == 0) ? v : ((p == 1) ? v * v : v * v * v);
            o[j] = (_Float16)pw;
        }
        *(half8v*)&dst[((size_t)(ck * 4 + q) * PADIMG + px) * 8] = o;
    }
}

// ---- Dispatch 5: final 3x3 conv, direct fp32 output + bias, oc-32. grid 512.
__global__ __launch_bounds__(256) void k_conv3o(const _Float16* __restrict__ upad,
                                                const _Float16* __restrict__ wout,
                                                const float* __restrict__ ob,
                                                float* __restrict__ out) {
    __shared__ __align__(16) float ts[32 * 68];
    conv3d32(blockIdx.x, threadIdx.x, ts, upad, wout, ob, nullptr, out);
}

extern "C" void kernel_launch(void* const* d_in, const int* in_sizes, int n_in,
                              void* d_out, int out_size, void* d_ws, size_t ws_size,
                              hipStream_t stream) {
    (void)in_sizes; (void)n_in; (void)out_size;
    const float* x  = (const float*)d_in[0];
    const float* tw = (const float*)d_in[1];
    const float* tb = (const float*)d_in[2];
    const float* cw = (const float*)d_in[3];
    const float* cb = (const float*)d_in[4];
    const float* bw = (const float*)d_in[5];
    const float* bb = (const float*)d_in[6];
    const float* ow = (const float*)d_in[7];
    const float* ob = (const float*)d_in[8];
    float* ws  = (float*)d_ws;
    float* out = (float*)d_out;

    _Float16* wbf  = (_Float16*)(ws + WBFO);
    _Float16* wout = wbf + 110592;
    _Float16* xpad = (_Float16*)(ws + XPADO);   // also upad (aliased)
    _Float16* topb = (_Float16*)(ws + TOPO);
    _Float16* cenb = (_Float16*)(ws + CENO);
    _Float16* botb = (_Float16*)(ws + BOTO);

    // m-split count: 8 (grid 1024) when the workspace can hold the 16MB PV
    // buffer; otherwise fall back to the proven 4-split layout.
    int ms     = (ws_size >= NEED8) ? 8 : 4;
    int msoOff = (ms == 8) ? MSO8 : MSO4;
    int zsoOff = msoOff + ms * 512;

    hipLaunchKernelGGL(k_prep, dim3(1216), dim3(256), 0, stream, bw, ow, tw, cw, wbf, x, xpad);
    hipLaunchKernelGGL(k_convs, dim3(1024), dim3(256), 0, stream, xpad, wbf, tb, cb, bb, topb, cenb, botb);
    if (ms == 8)
        hipLaunchKernelGGL(k_attn<8>,  dim3(1024), dim3(256), 0, stream, ws, msoOff, zsoOff);
    else
        hipLaunchKernelGGL(k_attn<16>, dim3(512),  dim3(256), 0, stream, ws, msoOff, zsoOff);
    hipLaunchKernelGGL(k_finalu, dim3(256), dim3(512), 0, stream, x, ws, xpad, ms, msoOff, zsoOff);
    hipLaunchKernelGGL(k_conv3o, dim3(512), dim3(256), 0, stream, xpad, wout, ob, out);
}